// Round 9
// baseline (373.710 us; speedup 1.0000x reference)
//
#include <hip/hip_runtime.h>
#include <hip/hip_bf16.h>
#include <math.h>

// ---- problem constants ----
#define BB    2
#define CC    96
#define NHD   4
#define HDIM  24
#define LAT_  181
#define LON_  360
#define PT_   2
#define HH    186
#define WWID  360
#define WH_   6
#define WW_   12
#define NTOK  72
#define SH_   3
#define SW_   6
#define NWH_  31
#define NWW_  30
#define NWIN  930
#define SCALE_ 0.20412414523193154f   // 24^-0.5

typedef __attribute__((ext_vector_type(8))) short short8v;
typedef __attribute__((ext_vector_type(4))) float f32x4;

__device__ __forceinline__ unsigned short pk_bf16(float x) {
    __hip_bfloat16 h = __float2bfloat16(x);          // RNE, v_cvt hw path
    union { __hip_bfloat16 b; unsigned short u; } cv; cv.b = h; return cv.u;
}
__device__ __forceinline__ uint2 pk4(float a, float b, float c, float d) {
    __hip_bfloat162 lo = __float22bfloat162_rn(make_float2(a, b));
    __hip_bfloat162 hi = __float22bfloat162_rn(make_float2(c, d));
    union { __hip_bfloat162 b; unsigned u; } c0, c1; c0.b = lo; c1.b = hi;
    uint2 r; r.x = c0.u; r.y = c1.u; return r;
}

// ---------------- pad + NCHW->NHWC via LDS tile transpose ----------------
__global__ __launch_bounds__(256) void k_pad2(const float* __restrict__ in, float* __restrict__ X) {
    int bid = blockIdx.x;
    int ct = bid % 3; bid /= 3;
    int wt = bid % 12; bid /= 12;
    int h = bid % HH; int b = bid / HH;
    int lat = h - PT_;
    int tx = threadIdx.x & 31, ty = threadIdx.x >> 5;
    __shared__ float tile[32][33];
    if (lat >= 0 && lat < LAT_) {
        int w = wt * 32 + tx;
        #pragma unroll
        for (int i = 0; i < 4; ++i) {
            int c = ct * 32 + ty + 8 * i;
            float v = 0.f;
            if (w < WWID) v = in[((long)(b * CC + c)) * (LAT_ * LON_) + lat * LON_ + w];
            tile[ty + 8 * i][tx] = v;
        }
    } else {
        #pragma unroll
        for (int i = 0; i < 4; ++i) tile[ty + 8 * i][tx] = 0.f;
    }
    __syncthreads();
    #pragma unroll
    for (int i = 0; i < 4; ++i) {
        int w = wt * 32 + ty + 8 * i;
        if (w < WWID)
            X[(((long)(b * HH + h)) * WWID + w) * CC + ct * 32 + tx] = tile[tx][ty + 8 * i];
    }
}

// ---------------- crop + NHWC->NCHW via LDS tile transpose ----------------
__global__ __launch_bounds__(256) void k_crop2(const float* __restrict__ X, float* __restrict__ out) {
    int bid = blockIdx.x;
    int ct = bid % 3; bid /= 3;
    int wt = bid % 12; bid /= 12;
    int lat = bid % LAT_; int b = bid / LAT_;
    int h = lat + PT_;
    int tx = threadIdx.x & 31, ty = threadIdx.x >> 5;
    __shared__ float tile[32][33];
    #pragma unroll
    for (int i = 0; i < 4; ++i) {
        int w = wt * 32 + ty + 8 * i;
        if (w < WWID)
            tile[ty + 8 * i][tx] = X[(((long)(b * HH + h)) * WWID + w) * CC + ct * 32 + tx];
    }
    __syncthreads();
    {
        int w = wt * 32 + tx;
        if (w < WWID) {
            #pragma unroll
            for (int i = 0; i < 4; ++i) {
                int c = ct * 32 + ty + 8 * i;
                out[((long)(b * CC + c)) * (LAT_ * LON_) + lat * LON_ + w] = tile[tx][ty + 8 * i];
            }
        }
    }
}

// ---------------- weight prep + bias/mask tables ----------------
__global__ void k_wprep(const float* __restrict__ f1w, const float* __restrict__ f2w,
                        const float* __restrict__ qkvw, const float* __restrict__ projw,
                        const float* __restrict__ rpb,
                        unsigned short* __restrict__ wbf, float* __restrict__ biasg) {
    int id = blockIdx.x * 256 + threadIdx.x;   // 425984 total
    if (id < 73728) {
        int layer = id / 36864, rem = id % 36864;
        int ks = rem / 12288, r2 = rem % 12288;
        int nt = r2 / 512, r3 = r2 % 512;
        int lane = r3 / 8, e = r3 % 8;
        int o = nt * 16 + (lane & 15);
        int c = ks * 32 + 8 * (lane >> 4) + e;
        wbf[(long)layer * 36864 + rem] = pk_bf16(f1w[((long)layer * 384 + o) * 96 + c]);
    } else if (id < 147456) {
        int id2 = id - 73728;
        int layer = id2 / 36864, rem = id2 % 36864;
        int ks = rem / 3072, r2 = rem % 3072;
        int nt = r2 / 512, r3 = r2 % 512;
        int lane = r3 / 8, e = r3 % 8;
        int o = nt * 16 + (lane & 15);
        int c = ks * 32 + 8 * (lane >> 4) + e;
        wbf[73728 + (long)layer * 36864 + rem] = pk_bf16(f2w[((long)layer * 96 + o) * 384 + c]);
    } else if (id < 202752) {
        wbf[id] = pk_bf16(qkvw[id - 147456]);
    } else if (id < 221184) {
        wbf[id] = pk_bf16(projw[id - 202752]);
    } else {
        int id2 = id - 221184;                 // 0..204799
        int layer = id2 / 102400, r = id2 % 102400;
        int type = r / 25600; r %= 25600;
        int h = r / 6400; r %= 6400;
        int i = r / 80, j = r % 80;
        float v;
        if (i >= 72 || j >= 72) {
            v = -10000.f;
        } else {
            int thi = i / 12, twi = i % 12, thj = j / 12, twj = j % 12;
            int ridx = (thi - thj + 5) * 23 + (twi - twj + 11);
            v = rpb[(layer * 253 + ridx) * 4 + h];
            if (layer == 1) {
                int eh = type & 1, ew = type >> 1;
                int ri = (eh ? (thi < 3 ? 1 : 2) * 3 : 0) + (ew ? (twi < 6 ? 1 : 2) : 0);
                int rj = (eh ? (thj < 3 ? 1 : 2) * 3 : 0) + (ew ? (twj < 6 ? 1 : 2) : 0);
                if (ri != rj) v -= 100.f;
            }
        }
        biasg[id2] = v;
    }
}

// ---------------- fused LN1 + attn + proj + LN2 + MLP (full block per window) ----------------
// LDS (127232 B), phase-multiplexed:
//   phases 0-2: [0,53248) As [80][104]b16 / psw[16 waves][16][104]b16 (alias)
//               [53248) qs [4][80][24]b16 | [68608) ks | [83968) vt [4][32][104]b16 | [110592) os [80][104]b16
//   phases 3+:  [0,33280) Xn f32 [80][104] | [33280,49920) A2s [80][104]b16 | [53248,115968) Hs [80][392]b16
template <int SHIFT>
__global__ __launch_bounds__(1024, 4) void k_attn(float* __restrict__ X,
        const float* __restrict__ gg, const float* __restrict__ bb,
        const unsigned short* __restrict__ wqkv, const float* __restrict__ qkvb,
        const unsigned short* __restrict__ wprj, const float* __restrict__ projb,
        const float* __restrict__ biasT,
        const float* __restrict__ g2, const float* __restrict__ b2,
        const unsigned short* __restrict__ w1f, const float* __restrict__ b1v,
        const unsigned short* __restrict__ w2f, const float* __restrict__ b2v) {
    __shared__ __align__(16) unsigned char smem[127232];
    unsigned short* As  = (unsigned short*)smem;
    unsigned short* psw0= (unsigned short*)smem;
    unsigned short* qs  = (unsigned short*)(smem + 53248);
    unsigned short* ks  = (unsigned short*)(smem + 68608);
    unsigned short* vt  = (unsigned short*)(smem + 83968);
    unsigned short* os  = (unsigned short*)(smem + 110592);
    float* Xn           = (float*)smem;                      // phase 3+
    unsigned short* A2s = (unsigned short*)(smem + 33280);   // phase 4+
    unsigned short* Hs  = (unsigned short*)(smem + 53248);   // phase 5+

    int bid = blockIdx.x;
    int b = bid / NWIN, wi = bid % NWIN;
    int nwh = wi / NWW_, nww = wi % NWW_;
    int tid = threadIdx.x;
    int wv = tid >> 6, lane = tid & 63;
    int li = lane & 15, gq = lane >> 4;

    int type = SHIFT ? ((nwh == 30 ? 1 : 0) | (nww == 29 ? 2 : 0)) : 0;
    const float* bias_t = biasT + type * 25600;

    // ---- phase 0: zero pads + gather window + LN1 -> As ----
    {
        unsigned* vz = (unsigned*)vt;
        for (int idx = tid; idx < 6656; idx += 1024) vz[idx] = 0u;
        unsigned* az = (unsigned*)(As + 72 * 104);
        for (int idx = tid; idx < 416; idx += 1024) az[idx] = 0u;
    }
    {
        int sub = lane >> 3, p = lane & 7;
        int t = wv * 8 + sub;
        if (t < 72) {
            int th = t / 12, tw = t % 12;
            int hr = nwh * WH_ + th, wr = nww * WW_ + tw;
            int ho = SHIFT ? (hr + SH_) % HH : hr;
            int wo = SHIFT ? (wr + SW_) % WWID : wr;
            const float* xr = X + (((long)b * HH + ho) * WWID + wo) * CC;
            float4 a  = *(const float4*)(xr + p * 4);
            float4 c4 = *(const float4*)(xr + p * 4 + 32);
            float4 e4 = *(const float4*)(xr + p * 4 + 64);
            float s  = a.x + a.y + a.z + a.w + c4.x + c4.y + c4.z + c4.w + e4.x + e4.y + e4.z + e4.w;
            float sq = a.x*a.x + a.y*a.y + a.z*a.z + a.w*a.w + c4.x*c4.x + c4.y*c4.y + c4.z*c4.z + c4.w*c4.w
                     + e4.x*e4.x + e4.y*e4.y + e4.z*e4.z + e4.w*e4.w;
            #pragma unroll
            for (int off = 1; off < 8; off <<= 1) {
                s  += __shfl_xor(s, off);
                sq += __shfl_xor(sq, off);
            }
            float mean = s * (1.f / CC);
            float var = sq * (1.f / CC) - mean * mean;
            float rs = rsqrtf(var + 1e-5f);
            float4 g0 = *(const float4*)(gg + p * 4);
            float4 g1v = *(const float4*)(gg + p * 4 + 32);
            float4 g2v = *(const float4*)(gg + p * 4 + 64);
            float4 t0 = *(const float4*)(bb + p * 4);
            float4 t1 = *(const float4*)(bb + p * 4 + 32);
            float4 t2 = *(const float4*)(bb + p * 4 + 64);
            *(uint2*)(As + t * 104 + p * 4) =
                pk4((a.x - mean) * rs * g0.x + t0.x, (a.y - mean) * rs * g0.y + t0.y,
                    (a.z - mean) * rs * g0.z + t0.z, (a.w - mean) * rs * g0.w + t0.w);
            *(uint2*)(As + t * 104 + p * 4 + 32) =
                pk4((c4.x - mean) * rs * g1v.x + t1.x, (c4.y - mean) * rs * g1v.y + t1.y,
                    (c4.z - mean) * rs * g1v.z + t1.z, (c4.w - mean) * rs * g1v.w + t1.w);
            *(uint2*)(As + t * 104 + p * 4 + 64) =
                pk4((e4.x - mean) * rs * g2v.x + t2.x, (e4.y - mean) * rs * g2v.y + t2.y,
                    (e4.z - mean) * rs * g2v.z + t2.z, (e4.w - mean) * rs * g2v.w + t2.w);
        }
    }
    __syncthreads();

    // ---- phase 1: QKV ----
    for (int mt = wv; mt < 18; mt += 16) {
        short8v aw[3];
        #pragma unroll
        for (int ksi = 0; ksi < 3; ++ksi)
            aw[ksi] = *(const short8v*)(wqkv + (mt * 16 + li) * 96 + ksi * 32 + 8 * gq);
        float bias4[4];
        #pragma unroll
        for (int r = 0; r < 4; ++r) bias4[r] = qkvb[mt * 16 + 4 * gq + r];
        f32x4 acc[5];
        #pragma unroll
        for (int nt = 0; nt < 5; ++nt) acc[nt] = (f32x4){0.f, 0.f, 0.f, 0.f};
        #pragma unroll
        for (int nt = 0; nt < 5; ++nt)
            #pragma unroll
            for (int ksi = 0; ksi < 3; ++ksi) {
                short8v by = *(const short8v*)(As + (nt * 16 + li) * 104 + ksi * 32 + 8 * gq);
                acc[nt] = __builtin_amdgcn_mfma_f32_16x16x32_bf16(aw[ksi], by, acc[nt], 0, 0, 0);
            }
        int which = mt / 6, mtl = mt % 6;
        int oo0 = mtl * 16 + 4 * gq;
        int h = oo0 / 24, d0 = oo0 % 24;
        #pragma unroll
        for (int nt = 0; nt < 5; ++nt) {
            int token = nt * 16 + li;
            if (which == 2) {
                #pragma unroll
                for (int r = 0; r < 4; ++r)
                    vt[(h * 32 + d0 + r) * 104 + token] = pk_bf16(acc[nt][r] + bias4[r]);
            } else {
                float v0 = acc[nt][0] + bias4[0], v1 = acc[nt][1] + bias4[1];
                float v2 = acc[nt][2] + bias4[2], v3 = acc[nt][3] + bias4[3];
                if (which == 0) { v0 *= SCALE_; v1 *= SCALE_; v2 *= SCALE_; v3 *= SCALE_; }
                unsigned short* dst = (which == 0 ? qs : ks) + (h * 80 + token) * 24 + d0;
                *(uint2*)dst = pk4(v0, v1, v2, v3);
            }
        }
    }
    __syncthreads();

    // ---- phase 2: fused S + PV -> os ----
    for (int u = wv; u < 20; u += 16) {
        int h = u / 5, nt = u % 5;
        unsigned short* psw = psw0 + (size_t)wv * (16 * 104);
        *(uint2*)(psw + li * 104 + 80 + 4 * gq) = (uint2){0u, 0u};
        short8v bq = {0,0,0,0,0,0,0,0};
        if (gq < 3) bq = *(const short8v*)(qs + (h * 80 + nt * 16 + li) * 24 + 8 * gq);
        const float* brow = bias_t + (h * 80 + nt * 16 + li) * 80;
        float p[20];
        float sum = 0.f;
        #pragma unroll
        for (int mt = 0; mt < 5; ++mt) {
            short8v ak = {0,0,0,0,0,0,0,0};
            if (gq < 3) ak = *(const short8v*)(ks + (h * 80 + mt * 16 + li) * 24 + 8 * gq);
            f32x4 ct = __builtin_amdgcn_mfma_f32_16x16x32_bf16(ak, bq, (f32x4){0.f,0.f,0.f,0.f}, 0, 0, 0);
            float4 bv = *(const float4*)(brow + mt * 16 + 4 * gq);
            p[mt*4+0] = __expf(ct[0] + bv.x);
            p[mt*4+1] = __expf(ct[1] + bv.y);
            p[mt*4+2] = __expf(ct[2] + bv.z);
            p[mt*4+3] = __expf(ct[3] + bv.w);
            sum += p[mt*4+0] + p[mt*4+1] + p[mt*4+2] + p[mt*4+3];
        }
        sum += __shfl_xor(sum, 16);
        sum += __shfl_xor(sum, 32);
        float inv = sum > 0.f ? 1.f / sum : 0.f;
        #pragma unroll
        for (int mt = 0; mt < 5; ++mt)
            *(uint2*)(psw + li * 104 + mt * 16 + 4 * gq) =
                pk4(p[mt*4+0] * inv, p[mt*4+1] * inv, p[mt*4+2] * inv, p[mt*4+3] * inv);
        #pragma unroll
        for (int nt2 = 0; nt2 < 2; ++nt2) {
            f32x4 acc = (f32x4){0.f, 0.f, 0.f, 0.f};
            #pragma unroll
            for (int ksi = 0; ksi < 3; ++ksi) {
                short8v ap = *(const short8v*)(psw + li * 104 + ksi * 32 + 8 * gq);
                short8v bv = *(const short8v*)(vt + (h * 32 + nt2 * 16 + li) * 104 + ksi * 32 + 8 * gq);
                acc = __builtin_amdgcn_mfma_f32_16x16x32_bf16(ap, bv, acc, 0, 0, 0);
            }
            int d = nt2 * 16 + li;
            if (d < 24) {
                #pragma unroll
                for (int r = 0; r < 4; ++r)
                    os[(nt * 16 + 4 * gq + r) * 104 + h * 24 + d] = pk_bf16(acc[r]);
            }
        }
    }
    __syncthreads();

    // ---- phase 3: proj + residual -> Xn (LDS f32) ----
    for (int u = wv; u < 30; u += 16) {
        int mt = u / 6, nt = u % 6;
        f32x4 acc = (f32x4){0.f, 0.f, 0.f, 0.f};
        #pragma unroll
        for (int ksi = 0; ksi < 3; ++ksi) {
            short8v ao = *(const short8v*)(os + (mt * 16 + li) * 104 + ksi * 32 + 8 * gq);
            short8v bw = *(const short8v*)(wprj + (nt * 16 + li) * 96 + ksi * 32 + 8 * gq);
            acc = __builtin_amdgcn_mfma_f32_16x16x32_bf16(ao, bw, acc, 0, 0, 0);
        }
        int o = nt * 16 + li;
        float bo = projb[o];
        #pragma unroll
        for (int r = 0; r < 4; ++r) {
            int token = mt * 16 + 4 * gq + r;
            if (token < 72) {
                int th = token / 12, tw = token % 12;
                int hr = nwh * WH_ + th, wr = nww * WW_ + tw;
                int ho = SHIFT ? (hr + SH_) % HH : hr;
                int wo = SHIFT ? (wr + SW_) % WWID : wr;
                float xo = X[(((long)b * HH + ho) * WWID + wo) * CC + o];
                Xn[token * 104 + o] = xo + acc[r] + bo;
            }
        }
    }
    __syncthreads();

    // ---- phase 4: zero A2s pad rows + LN2 (Xn -> A2s bf16) ----
    {
        unsigned* az = (unsigned*)(A2s + 72 * 104);
        for (int idx = tid; idx < 416; idx += 1024) az[idx] = 0u;
    }
    {
        int sub = lane >> 3, p = lane & 7;
        int t = wv * 8 + sub;
        if (t < 72) {
            const float* xr = Xn + t * 104;
            float4 a  = *(const float4*)(xr + p * 4);
            float4 c4 = *(const float4*)(xr + p * 4 + 32);
            float4 e4 = *(const float4*)(xr + p * 4 + 64);
            float s  = a.x + a.y + a.z + a.w + c4.x + c4.y + c4.z + c4.w + e4.x + e4.y + e4.z + e4.w;
            float sq = a.x*a.x + a.y*a.y + a.z*a.z + a.w*a.w + c4.x*c4.x + c4.y*c4.y + c4.z*c4.z + c4.w*c4.w
                     + e4.x*e4.x + e4.y*e4.y + e4.z*e4.z + e4.w*e4.w;
            #pragma unroll
            for (int off = 1; off < 8; off <<= 1) {
                s  += __shfl_xor(s, off);
                sq += __shfl_xor(sq, off);
            }
            float mean = s * (1.f / CC);
            float var = sq * (1.f / CC) - mean * mean;
            float rs = rsqrtf(var + 1e-5f);
            float4 g0 = *(const float4*)(g2 + p * 4);
            float4 g1v = *(const float4*)(g2 + p * 4 + 32);
            float4 g2v = *(const float4*)(g2 + p * 4 + 64);
            float4 t0 = *(const float4*)(b2 + p * 4);
            float4 t1 = *(const float4*)(b2 + p * 4 + 32);
            float4 t2 = *(const float4*)(b2 + p * 4 + 64);
            *(uint2*)(A2s + t * 104 + p * 4) =
                pk4((a.x - mean) * rs * g0.x + t0.x, (a.y - mean) * rs * g0.y + t0.y,
                    (a.z - mean) * rs * g0.z + t0.z, (a.w - mean) * rs * g0.w + t0.w);
            *(uint2*)(A2s + t * 104 + p * 4 + 32) =
                pk4((c4.x - mean) * rs * g1v.x + t1.x, (c4.y - mean) * rs * g1v.y + t1.y,
                    (c4.z - mean) * rs * g1v.z + t1.z, (c4.w - mean) * rs * g1v.w + t1.w);
            *(uint2*)(A2s + t * 104 + p * 4 + 64) =
                pk4((e4.x - mean) * rs * g2v.x + t2.x, (e4.y - mean) * rs * g2v.y + t2.y,
                    (e4.z - mean) * rs * g2v.z + t2.z, (e4.w - mean) * rs * g2v.w + t2.w);
        }
    }
    __syncthreads();

    // ---- phase 5: fc1 + GELU -> Hs [80][392] ----
    for (int u = wv; u < 120; u += 16) {
        int mt = u / 24, nt = u % 24;
        short8v afr[3];
        #pragma unroll
        for (int ksi = 0; ksi < 3; ++ksi)
            afr[ksi] = *(const short8v*)(A2s + (mt * 16 + li) * 104 + ksi * 32 + 8 * gq);
        f32x4 acc = (f32x4){0.f, 0.f, 0.f, 0.f};
        const short8v* wb = (const short8v*)w1f;
        #pragma unroll
        for (int ksi = 0; ksi < 3; ++ksi) {
            short8v bfr = wb[(ksi * 24 + nt) * 64 + lane];
            acc = __builtin_amdgcn_mfma_f32_16x16x32_bf16(afr[ksi], bfr, acc, 0, 0, 0);
        }
        int n = nt * 16 + li;
        float bb1 = b1v[n];
        #pragma unroll
        for (int r = 0; r < 4; ++r) {
            float s = acc[r] + bb1;
            float z = s + 0.044715f * s * s * s;
            float gl = s / (1.f + __expf(-1.5957691216057308f * z));
            Hs[(mt * 16 + 4 * gq + r) * 392 + n] = pk_bf16(gl);
        }
    }
    __syncthreads();

    // ---- phase 6: fc2 + residual -> final global write ----
    for (int u = wv; u < 30; u += 16) {
        int mt = u / 6, nt = u % 6;
        f32x4 acc = (f32x4){0.f, 0.f, 0.f, 0.f};
        const short8v* wb2 = (const short8v*)w2f;
        #pragma unroll
        for (int ksi = 0; ksi < 12; ++ksi) {
            short8v a2 = *(const short8v*)(Hs + (mt * 16 + li) * 392 + ksi * 32 + 8 * gq);
            short8v bfr = wb2[(ksi * 6 + nt) * 64 + lane];
            acc = __builtin_amdgcn_mfma_f32_16x16x32_bf16(a2, bfr, acc, 0, 0, 0);
        }
        int n = nt * 16 + li;
        float bb2 = b2v[n];
        #pragma unroll
        for (int r = 0; r < 4; ++r) {
            int token = mt * 16 + 4 * gq + r;
            if (token < 72) {
                int th = token / 12, tw = token % 12;
                int hr = nwh * WH_ + th, wr = nww * WW_ + tw;
                int ho = SHIFT ? (hr + SH_) % HH : hr;
                int wo = SHIFT ? (wr + SW_) % WWID : wr;
                X[(((long)b * HH + ho) * WWID + wo) * CC + n] =
                    Xn[token * 104 + n] + acc[r] + bb2;
            }
        }
    }
}

extern "C" void kernel_launch(void* const* d_in, const int* in_sizes, int n_in,
                              void* d_out, int out_size, void* d_ws, size_t ws_size,
                              hipStream_t stream) {
    const float* x     = (const float*)d_in[0];
    const float* g1    = (const float*)d_in[1];
    const float* b1    = (const float*)d_in[2];
    const float* qkvw  = (const float*)d_in[3];
    const float* qkvb  = (const float*)d_in[4];
    const float* projw = (const float*)d_in[5];
    const float* projb = (const float*)d_in[6];
    const float* rpb   = (const float*)d_in[7];
    const float* g2    = (const float*)d_in[8];
    const float* b2    = (const float*)d_in[9];
    const float* f1w   = (const float*)d_in[10];
    const float* f1b   = (const float*)d_in[11];
    const float* f2w   = (const float*)d_in[12];
    const float* f2b   = (const float*)d_in[13];

    float* X = (float*)d_ws;                                  // 51.4 MB
    unsigned short* wbf = (unsigned short*)(X + (long)BB * HH * WWID * CC);
    float* biasg = (float*)(wbf + 221184);                    // 2 x 102400 f32

    k_pad2<<<BB * HH * 12 * 3, 256, 0, stream>>>(x, X);
    k_wprep<<<1664, 256, 0, stream>>>(f1w, f2w, qkvw, projw, rpb, wbf, biasg);

    for (int i = 0; i < 2; ++i) {
        const unsigned short* wqkv_bf = wbf + 147456 + (long)i * 27648;
        const unsigned short* wprj_bf = wbf + 202752 + (long)i * 9216;
        const unsigned short* w1f = wbf + (long)i * 36864;
        const unsigned short* w2f = wbf + 73728 + (long)i * 36864;
        if (i == 0) {
            k_attn<0><<<BB * NWIN, 1024, 0, stream>>>(X, g1, b1,
                wqkv_bf, qkvb, wprj_bf, projb, biasg,
                g2, b2, w1f, f1b, w2f, f2b);
        } else {
            k_attn<1><<<BB * NWIN, 1024, 0, stream>>>(X, g1 + CC, b1 + CC,
                wqkv_bf, qkvb + 3 * CC, wprj_bf, projb + CC, biasg + 102400,
                g2 + CC, b2 + CC, w1f, f1b + 4 * CC, w2f, f2b + CC);
        }
    }

    k_crop2<<<BB * LAT_ * 12 * 3, 256, 0, stream>>>(X, (float*)d_out);
}

// Round 10
// 306.050 us; speedup vs baseline: 1.2211x; 1.2211x over previous
//
#include <hip/hip_runtime.h>
#include <hip/hip_bf16.h>
#include <math.h>

// ---- problem constants ----
#define BB    2
#define CC    96
#define NHD   4
#define HDIM  24
#define LAT_  181
#define LON_  360
#define PT_   2
#define HH    186
#define WWID  360
#define WH_   6
#define WW_   12
#define NTOK  72
#define SH_   3
#define SW_   6
#define NWH_  31
#define NWW_  30
#define NWIN  930
#define SCALE_ 0.20412414523193154f   // 24^-0.5

typedef __attribute__((ext_vector_type(8))) short short8v;
typedef __attribute__((ext_vector_type(4))) float f32x4;

__device__ __forceinline__ unsigned short pk_bf16(float x) {
    __hip_bfloat16 h = __float2bfloat16(x);          // RNE, v_cvt hw path
    union { __hip_bfloat16 b; unsigned short u; } cv; cv.b = h; return cv.u;
}
__device__ __forceinline__ uint2 pk4(float a, float b, float c, float d) {
    __hip_bfloat162 lo = __float22bfloat162_rn(make_float2(a, b));
    __hip_bfloat162 hi = __float22bfloat162_rn(make_float2(c, d));
    union { __hip_bfloat162 b; unsigned u; } c0, c1; c0.b = lo; c1.b = hi;
    uint2 r; r.x = c0.u; r.y = c1.u; return r;
}

// ---------------- pad + NCHW->NHWC via LDS tile transpose ----------------
__global__ __launch_bounds__(256) void k_pad2(const float* __restrict__ in, float* __restrict__ X) {
    int bid = blockIdx.x;
    int ct = bid % 3; bid /= 3;
    int wt = bid % 12; bid /= 12;
    int h = bid % HH; int b = bid / HH;
    int lat = h - PT_;
    int tx = threadIdx.x & 31, ty = threadIdx.x >> 5;
    __shared__ float tile[32][33];
    if (lat >= 0 && lat < LAT_) {
        int w = wt * 32 + tx;
        #pragma unroll
        for (int i = 0; i < 4; ++i) {
            int c = ct * 32 + ty + 8 * i;
            float v = 0.f;
            if (w < WWID) v = in[((long)(b * CC + c)) * (LAT_ * LON_) + lat * LON_ + w];
            tile[ty + 8 * i][tx] = v;
        }
    } else {
        #pragma unroll
        for (int i = 0; i < 4; ++i) tile[ty + 8 * i][tx] = 0.f;
    }
    __syncthreads();
    #pragma unroll
    for (int i = 0; i < 4; ++i) {
        int w = wt * 32 + ty + 8 * i;
        if (w < WWID)
            X[(((long)(b * HH + h)) * WWID + w) * CC + ct * 32 + tx] = tile[tx][ty + 8 * i];
    }
}

// ---------------- crop + NHWC->NCHW via LDS tile transpose ----------------
__global__ __launch_bounds__(256) void k_crop2(const float* __restrict__ X, float* __restrict__ out) {
    int bid = blockIdx.x;
    int ct = bid % 3; bid /= 3;
    int wt = bid % 12; bid /= 12;
    int lat = bid % LAT_; int b = bid / LAT_;
    int h = lat + PT_;
    int tx = threadIdx.x & 31, ty = threadIdx.x >> 5;
    __shared__ float tile[32][33];
    #pragma unroll
    for (int i = 0; i < 4; ++i) {
        int w = wt * 32 + ty + 8 * i;
        if (w < WWID)
            tile[ty + 8 * i][tx] = X[(((long)(b * HH + h)) * WWID + w) * CC + ct * 32 + tx];
    }
    __syncthreads();
    {
        int w = wt * 32 + tx;
        if (w < WWID) {
            #pragma unroll
            for (int i = 0; i < 4; ++i) {
                int c = ct * 32 + ty + 8 * i;
                out[((long)(b * CC + c)) * (LAT_ * LON_) + lat * LON_ + w] = tile[tx][ty + 8 * i];
            }
        }
    }
}

// ---------------- weight prep + bias/mask tables ----------------
__global__ void k_wprep(const float* __restrict__ f1w, const float* __restrict__ f2w,
                        const float* __restrict__ qkvw, const float* __restrict__ projw,
                        const float* __restrict__ rpb,
                        unsigned short* __restrict__ wbf, float* __restrict__ biasg) {
    int id = blockIdx.x * 256 + threadIdx.x;   // 425984 total
    if (id < 73728) {
        int layer = id / 36864, rem = id % 36864;
        int ks = rem / 12288, r2 = rem % 12288;
        int nt = r2 / 512, r3 = r2 % 512;
        int lane = r3 / 8, e = r3 % 8;
        int o = nt * 16 + (lane & 15);
        int c = ks * 32 + 8 * (lane >> 4) + e;
        wbf[(long)layer * 36864 + rem] = pk_bf16(f1w[((long)layer * 384 + o) * 96 + c]);
    } else if (id < 147456) {
        int id2 = id - 73728;
        int layer = id2 / 36864, rem = id2 % 36864;
        int ks = rem / 3072, r2 = rem % 3072;
        int nt = r2 / 512, r3 = r2 % 512;
        int lane = r3 / 8, e = r3 % 8;
        int o = nt * 16 + (lane & 15);
        int c = ks * 32 + 8 * (lane >> 4) + e;
        wbf[73728 + (long)layer * 36864 + rem] = pk_bf16(f2w[((long)layer * 96 + o) * 384 + c]);
    } else if (id < 202752) {
        wbf[id] = pk_bf16(qkvw[id - 147456]);
    } else if (id < 221184) {
        wbf[id] = pk_bf16(projw[id - 202752]);
    } else {
        int id2 = id - 221184;                 // 0..204799
        int layer = id2 / 102400, r = id2 % 102400;
        int type = r / 25600; r %= 25600;
        int h = r / 6400; r %= 6400;
        int i = r / 80, j = r % 80;
        float v;
        if (i >= 72 || j >= 72) {
            v = -10000.f;
        } else {
            int thi = i / 12, twi = i % 12, thj = j / 12, twj = j % 12;
            int ridx = (thi - thj + 5) * 23 + (twi - twj + 11);
            v = rpb[(layer * 253 + ridx) * 4 + h];
            if (layer == 1) {
                int eh = type & 1, ew = type >> 1;
                int ri = (eh ? (thi < 3 ? 1 : 2) * 3 : 0) + (ew ? (twi < 6 ? 1 : 2) : 0);
                int rj = (eh ? (thj < 3 ? 1 : 2) * 3 : 0) + (ew ? (twj < 6 ? 1 : 2) : 0);
                if (ri != rj) v -= 100.f;
            }
        }
        biasg[id2] = v;
    }
}

// ---------------- fused LN1 + MFMA window attention (shuffle-PV, 74KB LDS -> 2 blocks/CU) ----------------
// LDS (73984 B):
//   [0)       As [80][104] bf16 (phases 0-1) | os [80][104] bf16 (alias, phases 2-3)
//   [16640)   qs [4][80][24] bf16
//   [32000)   ks [4][80][24] bf16
//   [47360)   vt [4][32][104] bf16 (V transposed: [h][d][token])
template <int SHIFT>
__global__ __launch_bounds__(1024, 8) void k_attn(float* __restrict__ X,
        const float* __restrict__ gg, const float* __restrict__ bb,
        const unsigned short* __restrict__ wqkv, const float* __restrict__ qkvb,
        const unsigned short* __restrict__ wprj, const float* __restrict__ projb,
        const float* __restrict__ biasT) {
    __shared__ __align__(16) unsigned char smem[73984];
    unsigned short* As  = (unsigned short*)smem;
    unsigned short* os  = (unsigned short*)smem;             // alias (As dead after phase 1)
    unsigned short* qs  = (unsigned short*)(smem + 16640);
    unsigned short* ks  = (unsigned short*)(smem + 32000);
    unsigned short* vt  = (unsigned short*)(smem + 47360);

    int bid = blockIdx.x;
    int b = bid / NWIN, wi = bid % NWIN;
    int nwh = wi / NWW_, nww = wi % NWW_;
    int tid = threadIdx.x;
    int wv = tid >> 6, lane = tid & 63;
    int li = lane & 15, gq = lane >> 4;

    int type = SHIFT ? ((nwh == 30 ? 1 : 0) | (nww == 29 ? 2 : 0)) : 0;
    const float* bias_t = biasT + type * 25600;

    // zero-init pad regions read by MFMA
    {
        unsigned* vz = (unsigned*)vt;
        for (int idx = tid; idx < 6656; idx += 1024) vz[idx] = 0u;
        unsigned* az = (unsigned*)(As + 72 * 104);
        for (int idx = tid; idx < 416; idx += 1024) az[idx] = 0u;
    }

    // ---- phase 0: gather window + LN1 -> As (bf16); 8 lanes per token ----
    {
        int sub = lane >> 3, p = lane & 7;
        int t = wv * 8 + sub;
        if (t < 72) {
            int th = t / 12, tw = t % 12;
            int hr = nwh * WH_ + th, wr = nww * WW_ + tw;
            int ho = SHIFT ? (hr + SH_) % HH : hr;
            int wo = SHIFT ? (wr + SW_) % WWID : wr;
            const float* xr = X + (((long)b * HH + ho) * WWID + wo) * CC;
            float4 a  = *(const float4*)(xr + p * 4);
            float4 c4 = *(const float4*)(xr + p * 4 + 32);
            float4 e4 = *(const float4*)(xr + p * 4 + 64);
            float s  = a.x + a.y + a.z + a.w + c4.x + c4.y + c4.z + c4.w + e4.x + e4.y + e4.z + e4.w;
            float sq = a.x*a.x + a.y*a.y + a.z*a.z + a.w*a.w + c4.x*c4.x + c4.y*c4.y + c4.z*c4.z + c4.w*c4.w
                     + e4.x*e4.x + e4.y*e4.y + e4.z*e4.z + e4.w*e4.w;
            #pragma unroll
            for (int off = 1; off < 8; off <<= 1) {
                s  += __shfl_xor(s, off);
                sq += __shfl_xor(sq, off);
            }
            float mean = s * (1.f / CC);
            float var = sq * (1.f / CC) - mean * mean;
            float rs = rsqrtf(var + 1e-5f);
            float4 g0 = *(const float4*)(gg + p * 4);
            float4 g1v = *(const float4*)(gg + p * 4 + 32);
            float4 g2v = *(const float4*)(gg + p * 4 + 64);
            float4 t0 = *(const float4*)(bb + p * 4);
            float4 t1 = *(const float4*)(bb + p * 4 + 32);
            float4 t2 = *(const float4*)(bb + p * 4 + 64);
            *(uint2*)(As + t * 104 + p * 4) =
                pk4((a.x - mean) * rs * g0.x + t0.x, (a.y - mean) * rs * g0.y + t0.y,
                    (a.z - mean) * rs * g0.z + t0.z, (a.w - mean) * rs * g0.w + t0.w);
            *(uint2*)(As + t * 104 + p * 4 + 32) =
                pk4((c4.x - mean) * rs * g1v.x + t1.x, (c4.y - mean) * rs * g1v.y + t1.y,
                    (c4.z - mean) * rs * g1v.z + t1.z, (c4.w - mean) * rs * g1v.w + t1.w);
            *(uint2*)(As + t * 104 + p * 4 + 64) =
                pk4((e4.x - mean) * rs * g2v.x + t2.x, (e4.y - mean) * rs * g2v.y + t2.y,
                    (e4.z - mean) * rs * g2v.z + t2.z, (e4.w - mean) * rs * g2v.w + t2.w);
        }
    }
    __syncthreads();

    // ---- phase 1: QKV: C[o][token] = Wqkv @ Y^T ----
    for (int mt = wv; mt < 18; mt += 16) {
        short8v aw[3];
        #pragma unroll
        for (int ksi = 0; ksi < 3; ++ksi)
            aw[ksi] = *(const short8v*)(wqkv + (mt * 16 + li) * 96 + ksi * 32 + 8 * gq);
        float bias4[4];
        #pragma unroll
        for (int r = 0; r < 4; ++r) bias4[r] = qkvb[mt * 16 + 4 * gq + r];
        f32x4 acc[5];
        #pragma unroll
        for (int nt = 0; nt < 5; ++nt) acc[nt] = (f32x4){0.f, 0.f, 0.f, 0.f};
        #pragma unroll
        for (int nt = 0; nt < 5; ++nt)
            #pragma unroll
            for (int ksi = 0; ksi < 3; ++ksi) {
                short8v by = *(const short8v*)(As + (nt * 16 + li) * 104 + ksi * 32 + 8 * gq);
                acc[nt] = __builtin_amdgcn_mfma_f32_16x16x32_bf16(aw[ksi], by, acc[nt], 0, 0, 0);
            }
        int which = mt / 6, mtl = mt % 6;
        int oo0 = mtl * 16 + 4 * gq;
        int h = oo0 / 24, d0 = oo0 % 24;
        #pragma unroll
        for (int nt = 0; nt < 5; ++nt) {
            int token = nt * 16 + li;
            if (which == 2) {
                #pragma unroll
                for (int r = 0; r < 4; ++r)
                    vt[(h * 32 + d0 + r) * 104 + token] = pk_bf16(acc[nt][r] + bias4[r]);
            } else {
                float v0 = acc[nt][0] + bias4[0], v1 = acc[nt][1] + bias4[1];
                float v2 = acc[nt][2] + bias4[2], v3 = acc[nt][3] + bias4[3];
                if (which == 0) { v0 *= SCALE_; v1 *= SCALE_; v2 *= SCALE_; v3 *= SCALE_; }
                unsigned short* dst = (which == 0 ? qs : ks) + (h * 80 + token) * 24 + d0;
                *(uint2*)dst = pk4(v0, v1, v2, v3);
            }
        }
    }
    __syncthreads();

    // ---- phase 2: fused S + PV per wave; P redistributed via in-wave shuffles ----
    // S output: thread (li,gq) holds P[j=mt*16+4gq+r][i0=nt*16+li] (r<4, mt<5).
    // PV A-frag needs: P[i0][j=ksi*32+8gq+e] (e<8). Same i0 (same li) -> shuffle
    // among lanes {li+16g}: src lane = li+16*(2*(gq&1)+(e>>2)), src reg p[8ksi+4*(gq>>1)+(e&3)].
    for (int u = wv; u < 20; u += 16) {
        int h = u / 5, nt = u % 5;
        short8v bq = {0,0,0,0,0,0,0,0};
        if (gq < 3) bq = *(const short8v*)(qs + (h * 80 + nt * 16 + li) * 24 + 8 * gq);
        const float* brow = bias_t + (h * 80 + nt * 16 + li) * 80;
        float p[20];
        float sum = 0.f;
        #pragma unroll
        for (int mt = 0; mt < 5; ++mt) {
            short8v ak = {0,0,0,0,0,0,0,0};
            if (gq < 3) ak = *(const short8v*)(ks + (h * 80 + mt * 16 + li) * 24 + 8 * gq);
            f32x4 ct = __builtin_amdgcn_mfma_f32_16x16x32_bf16(ak, bq, (f32x4){0.f,0.f,0.f,0.f}, 0, 0, 0);
            float4 bv = *(const float4*)(brow + mt * 16 + 4 * gq);
            p[mt*4+0] = __expf(ct[0] + bv.x);
            p[mt*4+1] = __expf(ct[1] + bv.y);
            p[mt*4+2] = __expf(ct[2] + bv.z);
            p[mt*4+3] = __expf(ct[3] + bv.w);
            sum += p[mt*4+0] + p[mt*4+1] + p[mt*4+2] + p[mt*4+3];
        }
        sum += __shfl_xor(sum, 16);
        sum += __shfl_xor(sum, 32);
        float inv = sum > 0.f ? 1.f / sum : 0.f;
        #pragma unroll
        for (int k2 = 0; k2 < 20; ++k2) p[k2] *= inv;

        short8v ap[3];
        #pragma unroll
        for (int ksi = 0; ksi < 3; ++ksi) {
            float pv[8];
            #pragma unroll
            for (int e = 0; e < 8; ++e) {
                int srcl = li + 16 * (2 * (gq & 1) + (e >> 2));
                float s0 = __shfl(p[8 * ksi + (e & 3)], srcl);
                float s1 = (ksi < 2) ? __shfl(p[8 * ksi + 4 + (e & 3)], srcl) : 0.f;
                pv[e] = (gq >= 2) ? s1 : s0;
            }
            uint2 lo = pk4(pv[0], pv[1], pv[2], pv[3]);
            uint2 hi = pk4(pv[4], pv[5], pv[6], pv[7]);
            union { uint4 u; short8v s; } cvt;
            cvt.u = make_uint4(lo.x, lo.y, hi.x, hi.y);
            ap[ksi] = cvt.s;
        }
        #pragma unroll
        for (int nt2 = 0; nt2 < 2; ++nt2) {
            f32x4 acc = (f32x4){0.f, 0.f, 0.f, 0.f};
            #pragma unroll
            for (int ksi = 0; ksi < 3; ++ksi) {
                short8v bv2 = *(const short8v*)(vt + (h * 32 + nt2 * 16 + li) * 104 + ksi * 32 + 8 * gq);
                acc = __builtin_amdgcn_mfma_f32_16x16x32_bf16(ap[ksi], bv2, acc, 0, 0, 0);
            }
            int d = nt2 * 16 + li;
            if (d < 24) {
                #pragma unroll
                for (int r = 0; r < 4; ++r)
                    os[(nt * 16 + 4 * gq + r) * 104 + h * 24 + d] = pk_bf16(acc[r]);
            }
        }
    }
    __syncthreads();

    // ---- phase 3: proj + residual scatter ----
    for (int u = wv; u < 30; u += 16) {
        int mt = u / 6, nt = u % 6;
        f32x4 acc = (f32x4){0.f, 0.f, 0.f, 0.f};
        #pragma unroll
        for (int ksi = 0; ksi < 3; ++ksi) {
            short8v ao = *(const short8v*)(os + (mt * 16 + li) * 104 + ksi * 32 + 8 * gq);
            short8v bw = *(const short8v*)(wprj + (nt * 16 + li) * 96 + ksi * 32 + 8 * gq);
            acc = __builtin_amdgcn_mfma_f32_16x16x32_bf16(ao, bw, acc, 0, 0, 0);
        }
        int o = nt * 16 + li;
        float bo = projb[o];
        #pragma unroll
        for (int r = 0; r < 4; ++r) {
            int token = mt * 16 + 4 * gq + r;
            if (token < 72) {
                int th = token / 12, tw = token % 12;
                int hr = nwh * WH_ + th, wr = nww * WW_ + tw;
                int ho = SHIFT ? (hr + SH_) % HH : hr;
                int wo = SHIFT ? (wr + SW_) % WWID : wr;
                X[(((long)b * HH + ho) * WWID + wo) * CC + o] += acc[r] + bo;
            }
        }
    }
}

// ---------------- fused LN2 + MFMA MLP (R8, validated) ----------------
__global__ __launch_bounds__(256, 4) void k_mlp_mfma(float* __restrict__ X,
        const float* __restrict__ g, const float* __restrict__ bta,
        const unsigned short* __restrict__ w1f, const float* __restrict__ b1v,
        const unsigned short* __restrict__ w2f, const float* __restrict__ b2v) {
    __shared__ __align__(16) unsigned short As[32 * 120];
    __shared__ __align__(16) unsigned short Hs[32 * 392];
    long tok0 = (long)blockIdx.x * 32;
    int tid = threadIdx.x;

    {
        int t = tid >> 3, p = tid & 7;
        const float* xr = X + (tok0 + t) * CC;
        float4 a = *(const float4*)(xr + p * 4);
        float4 b = *(const float4*)(xr + p * 4 + 32);
        float4 c4 = *(const float4*)(xr + p * 4 + 64);
        float s  = a.x + a.y + a.z + a.w + b.x + b.y + b.z + b.w + c4.x + c4.y + c4.z + c4.w;
        float sq = a.x*a.x + a.y*a.y + a.z*a.z + a.w*a.w + b.x*b.x + b.y*b.y + b.z*b.z + b.w*b.w
                 + c4.x*c4.x + c4.y*c4.y + c4.z*c4.z + c4.w*c4.w;
        #pragma unroll
        for (int off = 1; off < 8; off <<= 1) {
            s  += __shfl_xor(s, off);
            sq += __shfl_xor(sq, off);
        }
        float mean = s * (1.f / CC);
        float var = sq * (1.f / CC) - mean * mean;
        float rs = rsqrtf(var + 1e-5f);
        float4 g0 = *(const float4*)(g + p * 4);
        float4 g1 = *(const float4*)(g + p * 4 + 32);
        float4 g2 = *(const float4*)(g + p * 4 + 64);
        float4 t0 = *(const float4*)(bta + p * 4);
        float4 t1 = *(const float4*)(bta + p * 4 + 32);
        float4 t2 = *(const float4*)(bta + p * 4 + 64);
        unsigned short* arow = As + t * 120;
        *(uint2*)(arow + p * 4) =
            pk4((a.x - mean) * rs * g0.x + t0.x, (a.y - mean) * rs * g0.y + t0.y,
                (a.z - mean) * rs * g0.z + t0.z, (a.w - mean) * rs * g0.w + t0.w);
        *(uint2*)(arow + p * 4 + 32) =
            pk4((b.x - mean) * rs * g1.x + t1.x, (b.y - mean) * rs * g1.y + t1.y,
                (b.z - mean) * rs * g1.z + t1.z, (b.w - mean) * rs * g1.w + t1.w);
        *(uint2*)(arow + p * 4 + 64) =
            pk4((c4.x - mean) * rs * g2.x + t2.x, (c4.y - mean) * rs * g2.y + t2.y,
                (c4.z - mean) * rs * g2.z + t2.z, (c4.w - mean) * rs * g2.w + t2.w);
    }
    __syncthreads();

    int w = tid >> 6, lane = tid & 63;
    int wm = w & 1;
    int row = wm * 16 + (lane & 15);
    int kbase = 8 * (lane >> 4);

    {
        int wnh = w >> 1;
        short8v afr[3];
        #pragma unroll
        for (int ks = 0; ks < 3; ++ks)
            afr[ks] = *(const short8v*)(As + row * 120 + ks * 32 + kbase);
        f32x4 acc[12];
        #pragma unroll
        for (int j = 0; j < 12; ++j) acc[j] = (f32x4){0.f, 0.f, 0.f, 0.f};
        const short8v* wb = (const short8v*)w1f;
        #pragma unroll
        for (int j = 0; j < 12; ++j) {
            int nt = wnh * 12 + j;
            #pragma unroll
            for (int ks = 0; ks < 3; ++ks) {
                short8v bfr = wb[(ks * 24 + nt) * 64 + lane];
                acc[j] = __builtin_amdgcn_mfma_f32_16x16x32_bf16(afr[ks], bfr, acc[j], 0, 0, 0);
            }
        }
        #pragma unroll
        for (int j = 0; j < 12; ++j) {
            int n = (wnh * 12 + j) * 16 + (lane & 15);
            float bb = b1v[n];
            #pragma unroll
            for (int r = 0; r < 4; ++r) {
                float s = acc[j][r] + bb;
                float z = s + 0.044715f * s * s * s;
                float gl = s / (1.f + __expf(-1.5957691216057308f * z));
                Hs[(wm * 16 + 4 * (lane >> 4) + r) * 392 + n] = pk_bf16(gl);
            }
        }
    }
    __syncthreads();

    {
        int wnt0 = (w >> 1) * 3;
        f32x4 acc2[3];
        #pragma unroll
        for (int j = 0; j < 3; ++j) acc2[j] = (f32x4){0.f, 0.f, 0.f, 0.f};
        const short8v* wb2 = (const short8v*)w2f;
        #pragma unroll
        for (int ks = 0; ks < 12; ++ks) {
            short8v a2 = *(const short8v*)(Hs + row * 392 + ks * 32 + kbase);
            #pragma unroll
            for (int j = 0; j < 3; ++j) {
                short8v bfr = wb2[(ks * 6 + wnt0 + j) * 64 + lane];
                acc2[j] = __builtin_amdgcn_mfma_f32_16x16x32_bf16(a2, bfr, acc2[j], 0, 0, 0);
            }
        }
        #pragma unroll
        for (int j = 0; j < 3; ++j) {
            int n = (wnt0 + j) * 16 + (lane & 15);
            float bb = b2v[n];
            #pragma unroll
            for (int r = 0; r < 4; ++r) {
                long tok = tok0 + wm * 16 + 4 * (lane >> 4) + r;
                X[tok * CC + n] += acc2[j][r] + bb;
            }
        }
    }
}

extern "C" void kernel_launch(void* const* d_in, const int* in_sizes, int n_in,
                              void* d_out, int out_size, void* d_ws, size_t ws_size,
                              hipStream_t stream) {
    const float* x     = (const float*)d_in[0];
    const float* g1    = (const float*)d_in[1];
    const float* b1    = (const float*)d_in[2];
    const float* qkvw  = (const float*)d_in[3];
    const float* qkvb  = (const float*)d_in[4];
    const float* projw = (const float*)d_in[5];
    const float* projb = (const float*)d_in[6];
    const float* rpb   = (const float*)d_in[7];
    const float* g2    = (const float*)d_in[8];
    const float* b2    = (const float*)d_in[9];
    const float* f1w   = (const float*)d_in[10];
    const float* f1b   = (const float*)d_in[11];
    const float* f2w   = (const float*)d_in[12];
    const float* f2b   = (const float*)d_in[13];

    float* X = (float*)d_ws;                                  // 51.4 MB
    unsigned short* wbf = (unsigned short*)(X + (long)BB * HH * WWID * CC);
    float* biasg = (float*)(wbf + 221184);                    // 2 x 102400 f32

    const int ntok = BB * HH * WWID;

    k_pad2<<<BB * HH * 12 * 3, 256, 0, stream>>>(x, X);
    k_wprep<<<1664, 256, 0, stream>>>(f1w, f2w, qkvw, projw, rpb, wbf, biasg);

    for (int i = 0; i < 2; ++i) {
        const unsigned short* wqkv_bf = wbf + 147456 + (long)i * 27648;
        const unsigned short* wprj_bf = wbf + 202752 + (long)i * 9216;
        if (i == 0) {
            k_attn<0><<<BB * NWIN, 1024, 0, stream>>>(X, g1, b1,
                wqkv_bf, qkvb, wprj_bf, projb, biasg);
        } else {
            k_attn<1><<<BB * NWIN, 1024, 0, stream>>>(X, g1 + CC, b1 + CC,
                wqkv_bf, qkvb + 3 * CC, wprj_bf, projb + CC, biasg + 102400);
        }
        k_mlp_mfma<<<ntok / 32, 256, 0, stream>>>(X,
            g2 + i * CC, b2 + i * CC,
            wbf + (long)i * 36864, f1b + i * 4 * CC,
            wbf + 73728 + (long)i * 36864, f2b + i * CC);
    }

    k_crop2<<<BB * LAT_ * 12 * 3, 256, 0, stream>>>(X, (float*)d_out);
}

// Round 11
// 300.473 us; speedup vs baseline: 1.2437x; 1.0186x over previous
//
#include <hip/hip_runtime.h>
#include <hip/hip_bf16.h>
#include <math.h>

// ---- problem constants ----
#define BB    2
#define CC    96
#define NHD   4
#define HDIM  24
#define LAT_  181
#define LON_  360
#define PT_   2
#define HH    186
#define WWID  360
#define WH_   6
#define WW_   12
#define NTOK  72
#define SH_   3
#define SW_   6
#define NWH_  31
#define NWW_  30
#define NWIN  930
#define SCALE_ 0.20412414523193154f   // 24^-0.5
#define MTOK  64

typedef __attribute__((ext_vector_type(8))) short short8v;
typedef __attribute__((ext_vector_type(4))) float f32x4;

__device__ __forceinline__ unsigned short pk_bf16(float x) {
    __hip_bfloat16 h = __float2bfloat16(x);
    union { __hip_bfloat16 b; unsigned short u; } cv; cv.b = h; return cv.u;
}
__device__ __forceinline__ uint2 pk4(float a, float b, float c, float d) {
    __hip_bfloat162 lo = __float22bfloat162_rn(make_float2(a, b));
    __hip_bfloat162 hi = __float22bfloat162_rn(make_float2(c, d));
    union { __hip_bfloat162 b; unsigned u; } c0, c1; c0.b = lo; c1.b = hi;
    uint2 r; r.x = c0.u; r.y = c1.u; return r;
}

// ---------------- pad + NCHW->NHWC via LDS tile transpose ----------------
__global__ __launch_bounds__(256) void k_pad2(const float* __restrict__ in, float* __restrict__ X) {
    int bid = blockIdx.x;
    int ct = bid % 3; bid /= 3;
    int wt = bid % 12; bid /= 12;
    int h = bid % HH; int b = bid / HH;
    int lat = h - PT_;
    int tx = threadIdx.x & 31, ty = threadIdx.x >> 5;
    __shared__ float tile[32][33];
    if (lat >= 0 && lat < LAT_) {
        int w = wt * 32 + tx;
        #pragma unroll
        for (int i = 0; i < 4; ++i) {
            int c = ct * 32 + ty + 8 * i;
            float v = 0.f;
            if (w < WWID) v = in[((long)(b * CC + c)) * (LAT_ * LON_) + lat * LON_ + w];
            tile[ty + 8 * i][tx] = v;
        }
    } else {
        #pragma unroll
        for (int i = 0; i < 4; ++i) tile[ty + 8 * i][tx] = 0.f;
    }
    __syncthreads();
    #pragma unroll
    for (int i = 0; i < 4; ++i) {
        int w = wt * 32 + ty + 8 * i;
        if (w < WWID)
            X[(((long)(b * HH + h)) * WWID + w) * CC + ct * 32 + tx] = tile[tx][ty + 8 * i];
    }
}

// ---------------- crop + NHWC->NCHW via LDS tile transpose ----------------
__global__ __launch_bounds__(256) void k_crop2(const float* __restrict__ X, float* __restrict__ out) {
    int bid = blockIdx.x;
    int ct = bid % 3; bid /= 3;
    int wt = bid % 12; bid /= 12;
    int lat = bid % LAT_; int b = bid / LAT_;
    int h = lat + PT_;
    int tx = threadIdx.x & 31, ty = threadIdx.x >> 5;
    __shared__ float tile[32][33];
    #pragma unroll
    for (int i = 0; i < 4; ++i) {
        int w = wt * 32 + ty + 8 * i;
        if (w < WWID)
            tile[ty + 8 * i][tx] = X[(((long)(b * HH + h)) * WWID + w) * CC + ct * 32 + tx];
    }
    __syncthreads();
    {
        int w = wt * 32 + tx;
        if (w < WWID) {
            #pragma unroll
            for (int i = 0; i < 4; ++i) {
                int c = ct * 32 + ty + 8 * i;
                out[((long)(b * CC + c)) * (LAT_ * LON_) + lat * LON_ + w] = tile[tx][ty + 8 * i];
            }
        }
    }
}

// ---------------- weight prep + bias/mask tables ----------------
__global__ void k_wprep(const float* __restrict__ f1w, const float* __restrict__ f2w,
                        const float* __restrict__ qkvw, const float* __restrict__ projw,
                        const float* __restrict__ rpb,
                        unsigned short* __restrict__ wbf, float* __restrict__ biasg) {
    int id = blockIdx.x * 256 + threadIdx.x;   // 425984 total
    if (id < 73728) {
        int layer = id / 36864, rem = id % 36864;
        int ks = rem / 12288, r2 = rem % 12288;
        int nt = r2 / 512, r3 = r2 % 512;
        int lane = r3 / 8, e = r3 % 8;
        int o = nt * 16 + (lane & 15);
        int c = ks * 32 + 8 * (lane >> 4) + e;
        wbf[(long)layer * 36864 + rem] = pk_bf16(f1w[((long)layer * 384 + o) * 96 + c]);
    } else if (id < 147456) {
        int id2 = id - 73728;
        int layer = id2 / 36864, rem = id2 % 36864;
        int ks = rem / 3072, r2 = rem % 3072;
        int nt = r2 / 512, r3 = r2 % 512;
        int lane = r3 / 8, e = r3 % 8;
        int o = nt * 16 + (lane & 15);
        int c = ks * 32 + 8 * (lane >> 4) + e;
        wbf[73728 + (long)layer * 36864 + rem] = pk_bf16(f2w[((long)layer * 96 + o) * 384 + c]);
    } else if (id < 202752) {
        wbf[id] = pk_bf16(qkvw[id - 147456]);
    } else if (id < 221184) {
        wbf[id] = pk_bf16(projw[id - 202752]);
    } else {
        int id2 = id - 221184;                 // 0..204799
        int layer = id2 / 102400, r = id2 % 102400;
        int type = r / 25600; r %= 25600;
        int h = r / 6400; r %= 6400;
        int i = r / 80, j = r % 80;
        float v;
        if (i >= 72 || j >= 72) {
            v = -10000.f;
        } else {
            int thi = i / 12, twi = i % 12, thj = j / 12, twj = j % 12;
            int ridx = (thi - thj + 5) * 23 + (twi - twj + 11);
            v = rpb[(layer * 253 + ridx) * 4 + h];
            if (layer == 1) {
                int eh = type & 1, ew = type >> 1;
                int ri = (eh ? (thi < 3 ? 1 : 2) * 3 : 0) + (ew ? (twi < 6 ? 1 : 2) : 0);
                int rj = (eh ? (thj < 3 ? 1 : 2) * 3 : 0) + (ew ? (twj < 6 ? 1 : 2) : 0);
                if (ri != rj) v -= 100.f;
            }
        }
        biasg[id2] = v;
    }
}

// ---------------- fused LN1 + MFMA window attention (R10, validated) ----------------
// LDS (73984 B): As/os alias [80][104]b16 | qs [4][80][24] | ks [4][80][24] | vt [4][32][104]
template <int SHIFT>
__global__ __launch_bounds__(1024, 8) void k_attn(float* __restrict__ X,
        const float* __restrict__ gg, const float* __restrict__ bb,
        const unsigned short* __restrict__ wqkv, const float* __restrict__ qkvb,
        const unsigned short* __restrict__ wprj, const float* __restrict__ projb,
        const float* __restrict__ biasT) {
    __shared__ __align__(16) unsigned char smem[73984];
    unsigned short* As  = (unsigned short*)smem;
    unsigned short* os  = (unsigned short*)smem;
    unsigned short* qs  = (unsigned short*)(smem + 16640);
    unsigned short* ks  = (unsigned short*)(smem + 32000);
    unsigned short* vt  = (unsigned short*)(smem + 47360);

    int bid = blockIdx.x;
    int b = bid / NWIN, wi = bid % NWIN;
    int nwh = wi / NWW_, nww = wi % NWW_;
    int tid = threadIdx.x;
    int wv = tid >> 6, lane = tid & 63;
    int li = lane & 15, gq = lane >> 4;

    int type = SHIFT ? ((nwh == 30 ? 1 : 0) | (nww == 29 ? 2 : 0)) : 0;
    const float* bias_t = biasT + type * 25600;

    {
        unsigned* vz = (unsigned*)vt;
        for (int idx = tid; idx < 6656; idx += 1024) vz[idx] = 0u;
        unsigned* az = (unsigned*)(As + 72 * 104);
        for (int idx = tid; idx < 416; idx += 1024) az[idx] = 0u;
    }

    // ---- phase 0: gather window + LN1 -> As ----
    {
        int sub = lane >> 3, p = lane & 7;
        int t = wv * 8 + sub;
        if (t < 72) {
            int th = t / 12, tw = t % 12;
            int hr = nwh * WH_ + th, wr = nww * WW_ + tw;
            int ho = SHIFT ? (hr + SH_) % HH : hr;
            int wo = SHIFT ? (wr + SW_) % WWID : wr;
            const float* xr = X + (((long)b * HH + ho) * WWID + wo) * CC;
            float4 a  = *(const float4*)(xr + p * 4);
            float4 c4 = *(const float4*)(xr + p * 4 + 32);
            float4 e4 = *(const float4*)(xr + p * 4 + 64);
            float s  = a.x + a.y + a.z + a.w + c4.x + c4.y + c4.z + c4.w + e4.x + e4.y + e4.z + e4.w;
            float sq = a.x*a.x + a.y*a.y + a.z*a.z + a.w*a.w + c4.x*c4.x + c4.y*c4.y + c4.z*c4.z + c4.w*c4.w
                     + e4.x*e4.x + e4.y*e4.y + e4.z*e4.z + e4.w*e4.w;
            #pragma unroll
            for (int off = 1; off < 8; off <<= 1) {
                s  += __shfl_xor(s, off);
                sq += __shfl_xor(sq, off);
            }
            float mean = s * (1.f / CC);
            float var = sq * (1.f / CC) - mean * mean;
            float rs = rsqrtf(var + 1e-5f);
            float4 g0 = *(const float4*)(gg + p * 4);
            float4 g1v = *(const float4*)(gg + p * 4 + 32);
            float4 g2v = *(const float4*)(gg + p * 4 + 64);
            float4 t0 = *(const float4*)(bb + p * 4);
            float4 t1 = *(const float4*)(bb + p * 4 + 32);
            float4 t2 = *(const float4*)(bb + p * 4 + 64);
            *(uint2*)(As + t * 104 + p * 4) =
                pk4((a.x - mean) * rs * g0.x + t0.x, (a.y - mean) * rs * g0.y + t0.y,
                    (a.z - mean) * rs * g0.z + t0.z, (a.w - mean) * rs * g0.w + t0.w);
            *(uint2*)(As + t * 104 + p * 4 + 32) =
                pk4((c4.x - mean) * rs * g1v.x + t1.x, (c4.y - mean) * rs * g1v.y + t1.y,
                    (c4.z - mean) * rs * g1v.z + t1.z, (c4.w - mean) * rs * g1v.w + t1.w);
            *(uint2*)(As + t * 104 + p * 4 + 64) =
                pk4((e4.x - mean) * rs * g2v.x + t2.x, (e4.y - mean) * rs * g2v.y + t2.y,
                    (e4.z - mean) * rs * g2v.z + t2.z, (e4.w - mean) * rs * g2v.w + t2.w);
        }
    }
    __syncthreads();

    // ---- phase 1: QKV ----
    for (int mt = wv; mt < 18; mt += 16) {
        short8v aw[3];
        #pragma unroll
        for (int ksi = 0; ksi < 3; ++ksi)
            aw[ksi] = *(const short8v*)(wqkv + (mt * 16 + li) * 96 + ksi * 32 + 8 * gq);
        float bias4[4];
        #pragma unroll
        for (int r = 0; r < 4; ++r) bias4[r] = qkvb[mt * 16 + 4 * gq + r];
        f32x4 acc[5];
        #pragma unroll
        for (int nt = 0; nt < 5; ++nt) acc[nt] = (f32x4){0.f, 0.f, 0.f, 0.f};
        #pragma unroll
        for (int nt = 0; nt < 5; ++nt)
            #pragma unroll
            for (int ksi = 0; ksi < 3; ++ksi) {
                short8v by = *(const short8v*)(As + (nt * 16 + li) * 104 + ksi * 32 + 8 * gq);
                acc[nt] = __builtin_amdgcn_mfma_f32_16x16x32_bf16(aw[ksi], by, acc[nt], 0, 0, 0);
            }
        int which = mt / 6, mtl = mt % 6;
        int oo0 = mtl * 16 + 4 * gq;
        int h = oo0 / 24, d0 = oo0 % 24;
        #pragma unroll
        for (int nt = 0; nt < 5; ++nt) {
            int token = nt * 16 + li;
            if (which == 2) {
                #pragma unroll
                for (int r = 0; r < 4; ++r)
                    vt[(h * 32 + d0 + r) * 104 + token] = pk_bf16(acc[nt][r] + bias4[r]);
            } else {
                float v0 = acc[nt][0] + bias4[0], v1 = acc[nt][1] + bias4[1];
                float v2 = acc[nt][2] + bias4[2], v3 = acc[nt][3] + bias4[3];
                if (which == 0) { v0 *= SCALE_; v1 *= SCALE_; v2 *= SCALE_; v3 *= SCALE_; }
                unsigned short* dst = (which == 0 ? qs : ks) + (h * 80 + token) * 24 + d0;
                *(uint2*)dst = pk4(v0, v1, v2, v3);
            }
        }
    }
    __syncthreads();

    // ---- phase 2: fused S + PV, shuffle-transposed P ----
    for (int u = wv; u < 20; u += 16) {
        int h = u / 5, nt = u % 5;
        short8v bq = {0,0,0,0,0,0,0,0};
        if (gq < 3) bq = *(const short8v*)(qs + (h * 80 + nt * 16 + li) * 24 + 8 * gq);
        const float* brow = bias_t + (h * 80 + nt * 16 + li) * 80;
        float p[20];
        float sum = 0.f;
        #pragma unroll
        for (int mt = 0; mt < 5; ++mt) {
            short8v ak = {0,0,0,0,0,0,0,0};
            if (gq < 3) ak = *(const short8v*)(ks + (h * 80 + mt * 16 + li) * 24 + 8 * gq);
            f32x4 ct = __builtin_amdgcn_mfma_f32_16x16x32_bf16(ak, bq, (f32x4){0.f,0.f,0.f,0.f}, 0, 0, 0);
            float4 bv = *(const float4*)(brow + mt * 16 + 4 * gq);
            p[mt*4+0] = __expf(ct[0] + bv.x);
            p[mt*4+1] = __expf(ct[1] + bv.y);
            p[mt*4+2] = __expf(ct[2] + bv.z);
            p[mt*4+3] = __expf(ct[3] + bv.w);
            sum += p[mt*4+0] + p[mt*4+1] + p[mt*4+2] + p[mt*4+3];
        }
        sum += __shfl_xor(sum, 16);
        sum += __shfl_xor(sum, 32);
        float inv = sum > 0.f ? 1.f / sum : 0.f;
        #pragma unroll
        for (int k2 = 0; k2 < 20; ++k2) p[k2] *= inv;

        short8v ap[3];
        #pragma unroll
        for (int ksi = 0; ksi < 3; ++ksi) {
            float pv[8];
            #pragma unroll
            for (int e = 0; e < 8; ++e) {
                int srcl = li + 16 * (2 * (gq & 1) + (e >> 2));
                float s0 = __shfl(p[8 * ksi + (e & 3)], srcl);
                float s1 = (ksi < 2) ? __shfl(p[8 * ksi + 4 + (e & 3)], srcl) : 0.f;
                pv[e] = (gq >= 2) ? s1 : s0;
            }
            uint2 lo = pk4(pv[0], pv[1], pv[2], pv[3]);
            uint2 hi = pk4(pv[4], pv[5], pv[6], pv[7]);
            union { uint4 u; short8v s; } cvt;
            cvt.u = make_uint4(lo.x, lo.y, hi.x, hi.y);
            ap[ksi] = cvt.s;
        }
        #pragma unroll
        for (int nt2 = 0; nt2 < 2; ++nt2) {
            f32x4 acc = (f32x4){0.f, 0.f, 0.f, 0.f};
            #pragma unroll
            for (int ksi = 0; ksi < 3; ++ksi) {
                short8v bv2 = *(const short8v*)(vt + (h * 32 + nt2 * 16 + li) * 104 + ksi * 32 + 8 * gq);
                acc = __builtin_amdgcn_mfma_f32_16x16x32_bf16(ap[ksi], bv2, acc, 0, 0, 0);
            }
            int d = nt2 * 16 + li;
            if (d < 24) {
                #pragma unroll
                for (int r = 0; r < 4; ++r)
                    os[(nt * 16 + 4 * gq + r) * 104 + h * 24 + d] = pk_bf16(acc[r]);
            }
        }
    }
    __syncthreads();

    // ---- phase 3: proj + residual scatter ----
    for (int u = wv; u < 30; u += 16) {
        int mt = u / 6, nt = u % 6;
        f32x4 acc = (f32x4){0.f, 0.f, 0.f, 0.f};
        #pragma unroll
        for (int ksi = 0; ksi < 3; ++ksi) {
            short8v ao = *(const short8v*)(os + (mt * 16 + li) * 104 + ksi * 32 + 8 * gq);
            short8v bw = *(const short8v*)(wprj + (nt * 16 + li) * 96 + ksi * 32 + 8 * gq);
            acc = __builtin_amdgcn_mfma_f32_16x16x32_bf16(ao, bw, acc, 0, 0, 0);
        }
        int o = nt * 16 + li;
        float bo = projb[o];
        #pragma unroll
        for (int r = 0; r < 4; ++r) {
            int token = mt * 16 + 4 * gq + r;
            if (token < 72) {
                int th = token / 12, tw = token % 12;
                int hr = nwh * WH_ + th, wr = nww * WW_ + tw;
                int ho = SHIFT ? (hr + SH_) % HH : hr;
                int wo = SHIFT ? (wr + SW_) % WWID : wr;
                X[(((long)b * HH + ho) * WWID + wo) * CC + o] += acc[r] + bo;
            }
        }
    }
}

// ---------------- fused LN2 + MFMA MLP v2: 64 tokens, 8 waves, wave-owns-N weight reuse ----------------
__global__ __launch_bounds__(512, 4) void k_mlp2(float* __restrict__ X, int ntok,
        const float* __restrict__ g, const float* __restrict__ bta,
        const unsigned short* __restrict__ w1f, const float* __restrict__ b1v,
        const unsigned short* __restrict__ w2f, const float* __restrict__ b2v) {
    __shared__ __align__(16) unsigned short As[MTOK * 120];   // 15360 B
    __shared__ __align__(16) unsigned short Hs[MTOK * 392];   // 50176 B
    long tok0 = (long)blockIdx.x * MTOK;
    int tid = threadIdx.x;
    int wv = tid >> 6, lane = tid & 63;
    int li = lane & 15, gq = lane >> 4;

    // ---- LN: 8 lanes per token, 64 tokens ----
    {
        int t = tid >> 3, p = tid & 7;
        long gt = tok0 + t; if (gt >= ntok) gt = ntok - 1;   // clamp tail (writes guarded later)
        const float* xr = X + gt * CC;
        float4 a = *(const float4*)(xr + p * 4);
        float4 b = *(const float4*)(xr + p * 4 + 32);
        float4 c4 = *(const float4*)(xr + p * 4 + 64);
        float s  = a.x + a.y + a.z + a.w + b.x + b.y + b.z + b.w + c4.x + c4.y + c4.z + c4.w;
        float sq = a.x*a.x + a.y*a.y + a.z*a.z + a.w*a.w + b.x*b.x + b.y*b.y + b.z*b.z + b.w*b.w
                 + c4.x*c4.x + c4.y*c4.y + c4.z*c4.z + c4.w*c4.w;
        #pragma unroll
        for (int off = 1; off < 8; off <<= 1) {
            s  += __shfl_xor(s, off);
            sq += __shfl_xor(sq, off);
        }
        float mean = s * (1.f / CC);
        float var = sq * (1.f / CC) - mean * mean;
        float rs = rsqrtf(var + 1e-5f);
        float4 g0 = *(const float4*)(g + p * 4);
        float4 g1 = *(const float4*)(g + p * 4 + 32);
        float4 g2 = *(const float4*)(g + p * 4 + 64);
        float4 t0 = *(const float4*)(bta + p * 4);
        float4 t1 = *(const float4*)(bta + p * 4 + 32);
        float4 t2 = *(const float4*)(bta + p * 4 + 64);
        unsigned short* arow = As + t * 120;
        *(uint2*)(arow + p * 4) =
            pk4((a.x - mean) * rs * g0.x + t0.x, (a.y - mean) * rs * g0.y + t0.y,
                (a.z - mean) * rs * g0.z + t0.z, (a.w - mean) * rs * g0.w + t0.w);
        *(uint2*)(arow + p * 4 + 32) =
            pk4((b.x - mean) * rs * g1.x + t1.x, (b.y - mean) * rs * g1.y + t1.y,
                (b.z - mean) * rs * g1.z + t1.z, (b.w - mean) * rs * g1.w + t1.w);
        *(uint2*)(arow + p * 4 + 64) =
            pk4((c4.x - mean) * rs * g2.x + t2.x, (c4.y - mean) * rs * g2.y + t2.y,
                (c4.z - mean) * rs * g2.z + t2.z, (c4.w - mean) * rs * g2.w + t2.w);
    }
    __syncthreads();

    // ---- fc1: wave wv owns nt = 3*wv .. 3*wv+2, strips s<4; weights loaded once ----
    {
        const short8v* wb = (const short8v*)w1f;
        short8v bfr[3][3];
        #pragma unroll
        for (int j = 0; j < 3; ++j)
            #pragma unroll
            for (int ks = 0; ks < 3; ++ks)
                bfr[j][ks] = wb[(ks * 24 + wv * 3 + j) * 64 + lane];
        float bb[3];
        #pragma unroll
        for (int j = 0; j < 3; ++j) bb[j] = b1v[(wv * 3 + j) * 16 + li];
        #pragma unroll
        for (int s = 0; s < 4; ++s) {
            short8v afr[3];
            #pragma unroll
            for (int ks = 0; ks < 3; ++ks)
                afr[ks] = *(const short8v*)(As + (s * 16 + li) * 120 + ks * 32 + 8 * gq);
            #pragma unroll
            for (int j = 0; j < 3; ++j) {
                f32x4 acc = (f32x4){0.f, 0.f, 0.f, 0.f};
                #pragma unroll
                for (int ks = 0; ks < 3; ++ks)
                    acc = __builtin_amdgcn_mfma_f32_16x16x32_bf16(afr[ks], bfr[j][ks], acc, 0, 0, 0);
                int n = (wv * 3 + j) * 16 + li;
                #pragma unroll
                for (int r = 0; r < 4; ++r) {
                    float sv = acc[r] + bb[j];
                    float z = sv + 0.044715f * sv * sv * sv;
                    float gl = sv / (1.f + __expf(-1.5957691216057308f * z));
                    Hs[(s * 16 + 4 * gq + r) * 392 + n] = pk_bf16(gl);
                }
            }
        }
    }
    __syncthreads();

    // ---- fc2: waves 0-5 own ntc = wv; strips s<4; + residual, guarded write ----
    if (wv < 6) {
        const short8v* wb2 = (const short8v*)w2f;
        short8v bfr2[12];
        #pragma unroll
        for (int ks = 0; ks < 12; ++ks)
            bfr2[ks] = wb2[(ks * 6 + wv) * 64 + lane];
        int n = wv * 16 + li;
        float bb = b2v[n];
        #pragma unroll
        for (int s = 0; s < 4; ++s) {
            f32x4 acc = (f32x4){0.f, 0.f, 0.f, 0.f};
            #pragma unroll
            for (int ks = 0; ks < 12; ++ks) {
                short8v a2 = *(const short8v*)(Hs + (s * 16 + li) * 392 + ks * 32 + 8 * gq);
                acc = __builtin_amdgcn_mfma_f32_16x16x32_bf16(a2, bfr2[ks], acc, 0, 0, 0);
            }
            #pragma unroll
            for (int r = 0; r < 4; ++r) {
                long gt = tok0 + s * 16 + 4 * gq + r;
                if (gt < ntok) X[gt * CC + n] += acc[r] + bb;
            }
        }
    }
}

extern "C" void kernel_launch(void* const* d_in, const int* in_sizes, int n_in,
                              void* d_out, int out_size, void* d_ws, size_t ws_size,
                              hipStream_t stream) {
    const float* x     = (const float*)d_in[0];
    const float* g1    = (const float*)d_in[1];
    const float* b1    = (const float*)d_in[2];
    const float* qkvw  = (const float*)d_in[3];
    const float* qkvb  = (const float*)d_in[4];
    const float* projw = (const float*)d_in[5];
    const float* projb = (const float*)d_in[6];
    const float* rpb   = (const float*)d_in[7];
    const float* g2    = (const float*)d_in[8];
    const float* b2    = (const float*)d_in[9];
    const float* f1w   = (const float*)d_in[10];
    const float* f1b   = (const float*)d_in[11];
    const float* f2w   = (const float*)d_in[12];
    const float* f2b   = (const float*)d_in[13];

    float* X = (float*)d_ws;                                  // 51.4 MB
    unsigned short* wbf = (unsigned short*)(X + (long)BB * HH * WWID * CC);
    float* biasg = (float*)(wbf + 221184);                    // 2 x 102400 f32

    const int ntok = BB * HH * WWID;                          // 133920
    const int mlp_blocks = (ntok + MTOK - 1) / MTOK;          // 2093

    k_pad2<<<BB * HH * 12 * 3, 256, 0, stream>>>(x, X);
    k_wprep<<<1664, 256, 0, stream>>>(f1w, f2w, qkvw, projw, rpb, wbf, biasg);

    for (int i = 0; i < 2; ++i) {
        const unsigned short* wqkv_bf = wbf + 147456 + (long)i * 27648;
        const unsigned short* wprj_bf = wbf + 202752 + (long)i * 9216;
        if (i == 0) {
            k_attn<0><<<BB * NWIN, 1024, 0, stream>>>(X, g1, b1,
                wqkv_bf, qkvb, wprj_bf, projb, biasg);
        } else {
            k_attn<1><<<BB * NWIN, 1024, 0, stream>>>(X, g1 + CC, b1 + CC,
                wqkv_bf, qkvb + 3 * CC, wprj_bf, projb + CC, biasg + 102400);
        }
        k_mlp2<<<mlp_blocks, 512, 0, stream>>>(X, ntok,
            g2 + i * CC, b2 + i * CC,
            wbf + (long)i * 36864, f1b + i * 4 * CC,
            wbf + 73728 + (long)i * 36864, f2b + i * CC);
    }

    k_crop2<<<BB * LAT_ * 12 * 3, 256, 0, stream>>>(X, (float*)d_out);
}

// Round 12
// 300.031 us; speedup vs baseline: 1.2456x; 1.0015x over previous
//
#include <hip/hip_runtime.h>
#include <hip/hip_bf16.h>
#include <math.h>

// ---- problem constants ----
#define BB    2
#define CC    96
#define NHD   4
#define HDIM  24
#define LAT_  181
#define LON_  360
#define PT_   2
#define HH    186
#define WWID  360
#define WH_   6
#define WW_   12
#define NTOK  72
#define SH_   3
#define SW_   6
#define NWH_  31
#define NWW_  30
#define NWIN  930
#define SCALE_ 0.20412414523193154f   // 24^-0.5
#define MTOK  64

typedef __attribute__((ext_vector_type(8))) short short8v;
typedef __attribute__((ext_vector_type(4))) float f32x4;

__device__ __forceinline__ unsigned short pk_bf16(float x) {
    __hip_bfloat16 h = __float2bfloat16(x);
    union { __hip_bfloat16 b; unsigned short u; } cv; cv.b = h; return cv.u;
}
__device__ __forceinline__ uint2 pk4(float a, float b, float c, float d) {
    __hip_bfloat162 lo = __float22bfloat162_rn(make_float2(a, b));
    __hip_bfloat162 hi = __float22bfloat162_rn(make_float2(c, d));
    union { __hip_bfloat162 b; unsigned u; } c0, c1; c0.b = lo; c1.b = hi;
    uint2 r; r.x = c0.u; r.y = c1.u; return r;
}

// ---------------- pad + NCHW->NHWC via LDS tile transpose ----------------
__global__ __launch_bounds__(256) void k_pad2(const float* __restrict__ in, float* __restrict__ X) {
    int bid = blockIdx.x;
    int ct = bid % 3; bid /= 3;
    int wt = bid % 12; bid /= 12;
    int h = bid % HH; int b = bid / HH;
    int lat = h - PT_;
    int tx = threadIdx.x & 31, ty = threadIdx.x >> 5;
    __shared__ float tile[32][33];
    if (lat >= 0 && lat < LAT_) {
        int w = wt * 32 + tx;
        #pragma unroll
        for (int i = 0; i < 4; ++i) {
            int c = ct * 32 + ty + 8 * i;
            float v = 0.f;
            if (w < WWID) v = in[((long)(b * CC + c)) * (LAT_ * LON_) + lat * LON_ + w];
            tile[ty + 8 * i][tx] = v;
        }
    } else {
        #pragma unroll
        for (int i = 0; i < 4; ++i) tile[ty + 8 * i][tx] = 0.f;
    }
    __syncthreads();
    #pragma unroll
    for (int i = 0; i < 4; ++i) {
        int w = wt * 32 + ty + 8 * i;
        if (w < WWID)
            X[(((long)(b * HH + h)) * WWID + w) * CC + ct * 32 + tx] = tile[tx][ty + 8 * i];
    }
}

// ---------------- weight prep + bias/mask tables ----------------
__global__ void k_wprep(const float* __restrict__ f1w, const float* __restrict__ f2w,
                        const float* __restrict__ qkvw, const float* __restrict__ projw,
                        const float* __restrict__ rpb,
                        unsigned short* __restrict__ wbf, float* __restrict__ biasg) {
    int id = blockIdx.x * 256 + threadIdx.x;   // 425984 total
    if (id < 73728) {
        int layer = id / 36864, rem = id % 36864;
        int ks = rem / 12288, r2 = rem % 12288;
        int nt = r2 / 512, r3 = r2 % 512;
        int lane = r3 / 8, e = r3 % 8;
        int o = nt * 16 + (lane & 15);
        int c = ks * 32 + 8 * (lane >> 4) + e;
        wbf[(long)layer * 36864 + rem] = pk_bf16(f1w[((long)layer * 384 + o) * 96 + c]);
    } else if (id < 147456) {
        int id2 = id - 73728;
        int layer = id2 / 36864, rem = id2 % 36864;
        int ks = rem / 3072, r2 = rem % 3072;
        int nt = r2 / 512, r3 = r2 % 512;
        int lane = r3 / 8, e = r3 % 8;
        int o = nt * 16 + (lane & 15);
        int c = ks * 32 + 8 * (lane >> 4) + e;
        wbf[73728 + (long)layer * 36864 + rem] = pk_bf16(f2w[((long)layer * 96 + o) * 384 + c]);
    } else if (id < 202752) {
        wbf[id] = pk_bf16(qkvw[id - 147456]);
    } else if (id < 221184) {
        wbf[id] = pk_bf16(projw[id - 202752]);
    } else {
        int id2 = id - 221184;                 // 0..204799
        int layer = id2 / 102400, r = id2 % 102400;
        int type = r / 25600; r %= 25600;
        int h = r / 6400; r %= 6400;
        int i = r / 80, j = r % 80;
        float v;
        if (i >= 72 || j >= 72) {
            v = -10000.f;
        } else {
            int thi = i / 12, twi = i % 12, thj = j / 12, twj = j % 12;
            int ridx = (thi - thj + 5) * 23 + (twi - twj + 11);
            v = rpb[(layer * 253 + ridx) * 4 + h];
            if (layer == 1) {
                int eh = type & 1, ew = type >> 1;
                int ri = (eh ? (thi < 3 ? 1 : 2) * 3 : 0) + (ew ? (twi < 6 ? 1 : 2) : 0);
                int rj = (eh ? (thj < 3 ? 1 : 2) * 3 : 0) + (ew ? (twj < 6 ? 1 : 2) : 0);
                if (ri != rj) v -= 100.f;
            }
        }
        biasg[id2] = v;
    }
}

// ---------------- fused LN1 + MFMA window attention (R10, validated) ----------------
template <int SHIFT>
__global__ __launch_bounds__(1024, 8) void k_attn(float* __restrict__ X,
        const float* __restrict__ gg, const float* __restrict__ bb,
        const unsigned short* __restrict__ wqkv, const float* __restrict__ qkvb,
        const unsigned short* __restrict__ wprj, const float* __restrict__ projb,
        const float* __restrict__ biasT) {
    __shared__ __align__(16) unsigned char smem[73984];
    unsigned short* As  = (unsigned short*)smem;
    unsigned short* os  = (unsigned short*)smem;
    unsigned short* qs  = (unsigned short*)(smem + 16640);
    unsigned short* ks  = (unsigned short*)(smem + 32000);
    unsigned short* vt  = (unsigned short*)(smem + 47360);

    int bid = blockIdx.x;
    int b = bid / NWIN, wi = bid % NWIN;
    int nwh = wi / NWW_, nww = wi % NWW_;
    int tid = threadIdx.x;
    int wv = tid >> 6, lane = tid & 63;
    int li = lane & 15, gq = lane >> 4;

    int type = SHIFT ? ((nwh == 30 ? 1 : 0) | (nww == 29 ? 2 : 0)) : 0;
    const float* bias_t = biasT + type * 25600;

    {
        unsigned* vz = (unsigned*)vt;
        for (int idx = tid; idx < 6656; idx += 1024) vz[idx] = 0u;
        unsigned* az = (unsigned*)(As + 72 * 104);
        for (int idx = tid; idx < 416; idx += 1024) az[idx] = 0u;
    }

    // ---- phase 0: gather window + LN1 -> As ----
    {
        int sub = lane >> 3, p = lane & 7;
        int t = wv * 8 + sub;
        if (t < 72) {
            int th = t / 12, tw = t % 12;
            int hr = nwh * WH_ + th, wr = nww * WW_ + tw;
            int ho = SHIFT ? (hr + SH_) % HH : hr;
            int wo = SHIFT ? (wr + SW_) % WWID : wr;
            const float* xr = X + (((long)b * HH + ho) * WWID + wo) * CC;
            float4 a  = *(const float4*)(xr + p * 4);
            float4 c4 = *(const float4*)(xr + p * 4 + 32);
            float4 e4 = *(const float4*)(xr + p * 4 + 64);
            float s  = a.x + a.y + a.z + a.w + c4.x + c4.y + c4.z + c4.w + e4.x + e4.y + e4.z + e4.w;
            float sq = a.x*a.x + a.y*a.y + a.z*a.z + a.w*a.w + c4.x*c4.x + c4.y*c4.y + c4.z*c4.z + c4.w*c4.w
                     + e4.x*e4.x + e4.y*e4.y + e4.z*e4.z + e4.w*e4.w;
            #pragma unroll
            for (int off = 1; off < 8; off <<= 1) {
                s  += __shfl_xor(s, off);
                sq += __shfl_xor(sq, off);
            }
            float mean = s * (1.f / CC);
            float var = sq * (1.f / CC) - mean * mean;
            float rs = rsqrtf(var + 1e-5f);
            float4 g0 = *(const float4*)(gg + p * 4);
            float4 g1v = *(const float4*)(gg + p * 4 + 32);
            float4 g2v = *(const float4*)(gg + p * 4 + 64);
            float4 t0 = *(const float4*)(bb + p * 4);
            float4 t1 = *(const float4*)(bb + p * 4 + 32);
            float4 t2 = *(const float4*)(bb + p * 4 + 64);
            *(uint2*)(As + t * 104 + p * 4) =
                pk4((a.x - mean) * rs * g0.x + t0.x, (a.y - mean) * rs * g0.y + t0.y,
                    (a.z - mean) * rs * g0.z + t0.z, (a.w - mean) * rs * g0.w + t0.w);
            *(uint2*)(As + t * 104 + p * 4 + 32) =
                pk4((c4.x - mean) * rs * g1v.x + t1.x, (c4.y - mean) * rs * g1v.y + t1.y,
                    (c4.z - mean) * rs * g1v.z + t1.z, (c4.w - mean) * rs * g1v.w + t1.w);
            *(uint2*)(As + t * 104 + p * 4 + 64) =
                pk4((e4.x - mean) * rs * g2v.x + t2.x, (e4.y - mean) * rs * g2v.y + t2.y,
                    (e4.z - mean) * rs * g2v.z + t2.z, (e4.w - mean) * rs * g2v.w + t2.w);
        }
    }
    __syncthreads();

    // ---- phase 1: QKV ----
    for (int mt = wv; mt < 18; mt += 16) {
        short8v aw[3];
        #pragma unroll
        for (int ksi = 0; ksi < 3; ++ksi)
            aw[ksi] = *(const short8v*)(wqkv + (mt * 16 + li) * 96 + ksi * 32 + 8 * gq);
        float bias4[4];
        #pragma unroll
        for (int r = 0; r < 4; ++r) bias4[r] = qkvb[mt * 16 + 4 * gq + r];
        f32x4 acc[5];
        #pragma unroll
        for (int nt = 0; nt < 5; ++nt) acc[nt] = (f32x4){0.f, 0.f, 0.f, 0.f};
        #pragma unroll
        for (int nt = 0; nt < 5; ++nt)
            #pragma unroll
            for (int ksi = 0; ksi < 3; ++ksi) {
                short8v by = *(const short8v*)(As + (nt * 16 + li) * 104 + ksi * 32 + 8 * gq);
                acc[nt] = __builtin_amdgcn_mfma_f32_16x16x32_bf16(aw[ksi], by, acc[nt], 0, 0, 0);
            }
        int which = mt / 6, mtl = mt % 6;
        int oo0 = mtl * 16 + 4 * gq;
        int h = oo0 / 24, d0 = oo0 % 24;
        #pragma unroll
        for (int nt = 0; nt < 5; ++nt) {
            int token = nt * 16 + li;
            if (which == 2) {
                #pragma unroll
                for (int r = 0; r < 4; ++r)
                    vt[(h * 32 + d0 + r) * 104 + token] = pk_bf16(acc[nt][r] + bias4[r]);
            } else {
                float v0 = acc[nt][0] + bias4[0], v1 = acc[nt][1] + bias4[1];
                float v2 = acc[nt][2] + bias4[2], v3 = acc[nt][3] + bias4[3];
                if (which == 0) { v0 *= SCALE_; v1 *= SCALE_; v2 *= SCALE_; v3 *= SCALE_; }
                unsigned short* dst = (which == 0 ? qs : ks) + (h * 80 + token) * 24 + d0;
                *(uint2*)dst = pk4(v0, v1, v2, v3);
            }
        }
    }
    __syncthreads();

    // ---- phase 2: fused S + PV, shuffle-transposed P ----
    for (int u = wv; u < 20; u += 16) {
        int h = u / 5, nt = u % 5;
        short8v bq = {0,0,0,0,0,0,0,0};
        if (gq < 3) bq = *(const short8v*)(qs + (h * 80 + nt * 16 + li) * 24 + 8 * gq);
        const float* brow = bias_t + (h * 80 + nt * 16 + li) * 80;
        float p[20];
        float sum = 0.f;
        #pragma unroll
        for (int mt = 0; mt < 5; ++mt) {
            short8v ak = {0,0,0,0,0,0,0,0};
            if (gq < 3) ak = *(const short8v*)(ks + (h * 80 + mt * 16 + li) * 24 + 8 * gq);
            f32x4 ct = __builtin_amdgcn_mfma_f32_16x16x32_bf16(ak, bq, (f32x4){0.f,0.f,0.f,0.f}, 0, 0, 0);
            float4 bv = *(const float4*)(brow + mt * 16 + 4 * gq);
            p[mt*4+0] = __expf(ct[0] + bv.x);
            p[mt*4+1] = __expf(ct[1] + bv.y);
            p[mt*4+2] = __expf(ct[2] + bv.z);
            p[mt*4+3] = __expf(ct[3] + bv.w);
            sum += p[mt*4+0] + p[mt*4+1] + p[mt*4+2] + p[mt*4+3];
        }
        sum += __shfl_xor(sum, 16);
        sum += __shfl_xor(sum, 32);
        float inv = sum > 0.f ? 1.f / sum : 0.f;
        #pragma unroll
        for (int k2 = 0; k2 < 20; ++k2) p[k2] *= inv;

        short8v ap[3];
        #pragma unroll
        for (int ksi = 0; ksi < 3; ++ksi) {
            float pv[8];
            #pragma unroll
            for (int e = 0; e < 8; ++e) {
                int srcl = li + 16 * (2 * (gq & 1) + (e >> 2));
                float s0 = __shfl(p[8 * ksi + (e & 3)], srcl);
                float s1 = (ksi < 2) ? __shfl(p[8 * ksi + 4 + (e & 3)], srcl) : 0.f;
                pv[e] = (gq >= 2) ? s1 : s0;
            }
            uint2 lo = pk4(pv[0], pv[1], pv[2], pv[3]);
            uint2 hi = pk4(pv[4], pv[5], pv[6], pv[7]);
            union { uint4 u; short8v s; } cvt;
            cvt.u = make_uint4(lo.x, lo.y, hi.x, hi.y);
            ap[ksi] = cvt.s;
        }
        #pragma unroll
        for (int nt2 = 0; nt2 < 2; ++nt2) {
            f32x4 acc = (f32x4){0.f, 0.f, 0.f, 0.f};
            #pragma unroll
            for (int ksi = 0; ksi < 3; ++ksi) {
                short8v bv2 = *(const short8v*)(vt + (h * 32 + nt2 * 16 + li) * 104 + ksi * 32 + 8 * gq);
                acc = __builtin_amdgcn_mfma_f32_16x16x32_bf16(ap[ksi], bv2, acc, 0, 0, 0);
            }
            int d = nt2 * 16 + li;
            if (d < 24) {
                #pragma unroll
                for (int r = 0; r < 4; ++r)
                    os[(nt * 16 + 4 * gq + r) * 104 + h * 24 + d] = pk_bf16(acc[r]);
            }
        }
    }
    __syncthreads();

    // ---- phase 3: proj + residual scatter ----
    for (int u = wv; u < 30; u += 16) {
        int mt = u / 6, nt = u % 6;
        f32x4 acc = (f32x4){0.f, 0.f, 0.f, 0.f};
        #pragma unroll
        for (int ksi = 0; ksi < 3; ++ksi) {
            short8v ao = *(const short8v*)(os + (mt * 16 + li) * 104 + ksi * 32 + 8 * gq);
            short8v bw = *(const short8v*)(wprj + (nt * 16 + li) * 96 + ksi * 32 + 8 * gq);
            acc = __builtin_amdgcn_mfma_f32_16x16x32_bf16(ao, bw, acc, 0, 0, 0);
        }
        int o = nt * 16 + li;
        float bo = projb[o];
        #pragma unroll
        for (int r = 0; r < 4; ++r) {
            int token = mt * 16 + 4 * gq + r;
            if (token < 72) {
                int th = token / 12, tw = token % 12;
                int hr = nwh * WH_ + th, wr = nww * WW_ + tw;
                int ho = SHIFT ? (hr + SH_) % HH : hr;
                int wo = SHIFT ? (wr + SW_) % WWID : wr;
                X[(((long)b * HH + ho) * WWID + wo) * CC + o] += acc[r] + bo;
            }
        }
    }
}

// ---------------- fused LN2 + MFMA MLP v2; LAST=1 fuses the crop (writes NCHW out) ----------------
template <int LAST>
__global__ __launch_bounds__(512, 4) void k_mlp2(float* __restrict__ X, float* __restrict__ out, int ntok,
        const float* __restrict__ g, const float* __restrict__ bta,
        const unsigned short* __restrict__ w1f, const float* __restrict__ b1v,
        const unsigned short* __restrict__ w2f, const float* __restrict__ b2v) {
    __shared__ __align__(16) unsigned short As[MTOK * 120];
    __shared__ __align__(16) unsigned short Hs[MTOK * 392];
    long tok0 = (long)blockIdx.x * MTOK;
    int tid = threadIdx.x;
    int wv = tid >> 6, lane = tid & 63;
    int li = lane & 15, gq = lane >> 4;

    // ---- LN: 8 lanes per token, 64 tokens ----
    {
        int t = tid >> 3, p = tid & 7;
        long gt = tok0 + t; if (gt >= ntok) gt = ntok - 1;
        const float* xr = X + gt * CC;
        float4 a = *(const float4*)(xr + p * 4);
        float4 b = *(const float4*)(xr + p * 4 + 32);
        float4 c4 = *(const float4*)(xr + p * 4 + 64);
        float s  = a.x + a.y + a.z + a.w + b.x + b.y + b.z + b.w + c4.x + c4.y + c4.z + c4.w;
        float sq = a.x*a.x + a.y*a.y + a.z*a.z + a.w*a.w + b.x*b.x + b.y*b.y + b.z*b.z + b.w*b.w
                 + c4.x*c4.x + c4.y*c4.y + c4.z*c4.z + c4.w*c4.w;
        #pragma unroll
        for (int off = 1; off < 8; off <<= 1) {
            s  += __shfl_xor(s, off);
            sq += __shfl_xor(sq, off);
        }
        float mean = s * (1.f / CC);
        float var = sq * (1.f / CC) - mean * mean;
        float rs = rsqrtf(var + 1e-5f);
        float4 g0 = *(const float4*)(g + p * 4);
        float4 g1 = *(const float4*)(g + p * 4 + 32);
        float4 g2 = *(const float4*)(g + p * 4 + 64);
        float4 t0 = *(const float4*)(bta + p * 4);
        float4 t1 = *(const float4*)(bta + p * 4 + 32);
        float4 t2 = *(const float4*)(bta + p * 4 + 64);
        unsigned short* arow = As + t * 120;
        *(uint2*)(arow + p * 4) =
            pk4((a.x - mean) * rs * g0.x + t0.x, (a.y - mean) * rs * g0.y + t0.y,
                (a.z - mean) * rs * g0.z + t0.z, (a.w - mean) * rs * g0.w + t0.w);
        *(uint2*)(arow + p * 4 + 32) =
            pk4((b.x - mean) * rs * g1.x + t1.x, (b.y - mean) * rs * g1.y + t1.y,
                (b.z - mean) * rs * g1.z + t1.z, (b.w - mean) * rs * g1.w + t1.w);
        *(uint2*)(arow + p * 4 + 64) =
            pk4((c4.x - mean) * rs * g2.x + t2.x, (c4.y - mean) * rs * g2.y + t2.y,
                (c4.z - mean) * rs * g2.z + t2.z, (c4.w - mean) * rs * g2.w + t2.w);
    }
    __syncthreads();

    // ---- fc1: wave wv owns nt = 3*wv .. 3*wv+2 ----
    {
        const short8v* wb = (const short8v*)w1f;
        short8v bfr[3][3];
        #pragma unroll
        for (int j = 0; j < 3; ++j)
            #pragma unroll
            for (int ks = 0; ks < 3; ++ks)
                bfr[j][ks] = wb[(ks * 24 + wv * 3 + j) * 64 + lane];
        float bb[3];
        #pragma unroll
        for (int j = 0; j < 3; ++j) bb[j] = b1v[(wv * 3 + j) * 16 + li];
        #pragma unroll
        for (int s = 0; s < 4; ++s) {
            short8v afr[3];
            #pragma unroll
            for (int ks = 0; ks < 3; ++ks)
                afr[ks] = *(const short8v*)(As + (s * 16 + li) * 120 + ks * 32 + 8 * gq);
            #pragma unroll
            for (int j = 0; j < 3; ++j) {
                f32x4 acc = (f32x4){0.f, 0.f, 0.f, 0.f};
                #pragma unroll
                for (int ks = 0; ks < 3; ++ks)
                    acc = __builtin_amdgcn_mfma_f32_16x16x32_bf16(afr[ks], bfr[j][ks], acc, 0, 0, 0);
                int n = (wv * 3 + j) * 16 + li;
                #pragma unroll
                for (int r = 0; r < 4; ++r) {
                    float sv = acc[r] + bb[j];
                    float z = sv + 0.044715f * sv * sv * sv;
                    float gl = sv / (1.f + __expf(-1.5957691216057308f * z));
                    Hs[(s * 16 + 4 * gq + r) * 392 + n] = pk_bf16(gl);
                }
            }
        }
    }
    __syncthreads();

    // ---- fc2: waves 0-5 own nt = wv; + residual ----
    if (wv < 6) {
        const short8v* wb2 = (const short8v*)w2f;
        short8v bfr2[12];
        #pragma unroll
        for (int ks = 0; ks < 12; ++ks)
            bfr2[ks] = wb2[(ks * 6 + wv) * 64 + lane];
        int n = wv * 16 + li;
        float bb = b2v[n];
        // block-base token decode (for LAST crop-fused path)
        int b0 = 0, h0 = 0, w0 = 0;
        if (LAST) {
            b0 = (int)(tok0 / (HH * WWID));
            int rem0 = (int)(tok0 % (HH * WWID));
            h0 = rem0 / WWID; w0 = rem0 % WWID;
        }
        #pragma unroll
        for (int s = 0; s < 4; ++s) {
            f32x4 acc = (f32x4){0.f, 0.f, 0.f, 0.f};
            #pragma unroll
            for (int ks = 0; ks < 12; ++ks) {
                short8v a2 = *(const short8v*)(Hs + (s * 16 + li) * 392 + ks * 32 + 8 * gq);
                acc = __builtin_amdgcn_mfma_f32_16x16x32_bf16(a2, bfr2[ks], acc, 0, 0, 0);
            }
            #pragma unroll
            for (int r = 0; r < 4; ++r) {
                int o = s * 16 + 4 * gq + r;
                long gt = tok0 + o;
                if (gt < ntok) {
                    if (LAST) {
                        int w = w0 + o, h = h0, b = b0;
                        if (w >= WWID) { w -= WWID; h += 1; }
                        if (h >= HH) { h -= HH; b += 1; }
                        int lat = h - PT_;
                        if (lat >= 0 && lat < LAT_)
                            out[((long)(b * CC + n)) * (LAT_ * LON_) + lat * LON_ + w] =
                                X[gt * CC + n] + acc[r] + bb;
                    } else {
                        X[gt * CC + n] += acc[r] + bb;
                    }
                }
            }
        }
    }
}

extern "C" void kernel_launch(void* const* d_in, const int* in_sizes, int n_in,
                              void* d_out, int out_size, void* d_ws, size_t ws_size,
                              hipStream_t stream) {
    const float* x     = (const float*)d_in[0];
    const float* g1    = (const float*)d_in[1];
    const float* b1    = (const float*)d_in[2];
    const float* qkvw  = (const float*)d_in[3];
    const float* qkvb  = (const float*)d_in[4];
    const float* projw = (const float*)d_in[5];
    const float* projb = (const float*)d_in[6];
    const float* rpb   = (const float*)d_in[7];
    const float* g2    = (const float*)d_in[8];
    const float* b2    = (const float*)d_in[9];
    const float* f1w   = (const float*)d_in[10];
    const float* f1b   = (const float*)d_in[11];
    const float* f2w   = (const float*)d_in[12];
    const float* f2b   = (const float*)d_in[13];

    float* X = (float*)d_ws;                                  // 51.4 MB
    unsigned short* wbf = (unsigned short*)(X + (long)BB * HH * WWID * CC);
    float* biasg = (float*)(wbf + 221184);                    // 2 x 102400 f32

    const int ntok = BB * HH * WWID;                          // 133920
    const int mlp_blocks = (ntok + MTOK - 1) / MTOK;          // 2093

    k_pad2<<<BB * HH * 12 * 3, 256, 0, stream>>>(x, X);
    k_wprep<<<1664, 256, 0, stream>>>(f1w, f2w, qkvw, projw, rpb, wbf, biasg);

    for (int i = 0; i < 2; ++i) {
        const unsigned short* wqkv_bf = wbf + 147456 + (long)i * 27648;
        const unsigned short* wprj_bf = wbf + 202752 + (long)i * 9216;
        if (i == 0) {
            k_attn<0><<<BB * NWIN, 1024, 0, stream>>>(X, g1, b1,
                wqkv_bf, qkvb, wprj_bf, projb, biasg);
            k_mlp2<0><<<mlp_blocks, 512, 0, stream>>>(X, nullptr, ntok,
                g2, b2, wbf, f1b, wbf + 73728, f2b);
        } else {
            k_attn<1><<<BB * NWIN, 1024, 0, stream>>>(X, g1 + CC, b1 + CC,
                wqkv_bf, qkvb + 3 * CC, wprj_bf, projb + CC, biasg + 102400);
            k_mlp2<1><<<mlp_blocks, 512, 0, stream>>>(X, (float*)d_out, ntok,
                g2 + CC, b2 + CC, wbf + 36864, f1b + 4 * CC, wbf + 73728 + 36864, f2b + CC);
        }
    }
}

// Round 13
// 294.334 us; speedup vs baseline: 1.2697x; 1.0194x over previous
//
#include <hip/hip_runtime.h>
#include <hip/hip_bf16.h>
#include <math.h>

// ---- problem constants ----
#define BB    2
#define CC    96
#define NHD   4
#define HDIM  24
#define LAT_  181
#define LON_  360
#define PT_   2
#define HH    186
#define WWID  360
#define WH_   6
#define WW_   12
#define NTOK  72
#define SH_   3
#define SW_   6
#define NWH_  31
#define NWW_  30
#define NWIN  930
#define SCALE_ 0.20412414523193154f   // 24^-0.5
#define MTOK  48

typedef __attribute__((ext_vector_type(8))) short short8v;
typedef __attribute__((ext_vector_type(4))) float f32x4;

__device__ __forceinline__ unsigned short pk_bf16(float x) {
    __hip_bfloat16 h = __float2bfloat16(x);
    union { __hip_bfloat16 b; unsigned short u; } cv; cv.b = h; return cv.u;
}
__device__ __forceinline__ uint2 pk4(float a, float b, float c, float d) {
    __hip_bfloat162 lo = __float22bfloat162_rn(make_float2(a, b));
    __hip_bfloat162 hi = __float22bfloat162_rn(make_float2(c, d));
    union { __hip_bfloat162 b; unsigned u; } c0, c1; c0.b = lo; c1.b = hi;
    uint2 r; r.x = c0.u; r.y = c1.u; return r;
}

// ---------------- pad + NCHW->NHWC via LDS tile transpose ----------------
__global__ __launch_bounds__(256) void k_pad2(const float* __restrict__ in, float* __restrict__ X) {
    int bid = blockIdx.x;
    int ct = bid % 3; bid /= 3;
    int wt = bid % 12; bid /= 12;
    int h = bid % HH; int b = bid / HH;
    int lat = h - PT_;
    int tx = threadIdx.x & 31, ty = threadIdx.x >> 5;
    __shared__ float tile[32][33];
    if (lat >= 0 && lat < LAT_) {
        int w = wt * 32 + tx;
        #pragma unroll
        for (int i = 0; i < 4; ++i) {
            int c = ct * 32 + ty + 8 * i;
            float v = 0.f;
            if (w < WWID) v = in[((long)(b * CC + c)) * (LAT_ * LON_) + lat * LON_ + w];
            tile[ty + 8 * i][tx] = v;
        }
    } else {
        #pragma unroll
        for (int i = 0; i < 4; ++i) tile[ty + 8 * i][tx] = 0.f;
    }
    __syncthreads();
    #pragma unroll
    for (int i = 0; i < 4; ++i) {
        int w = wt * 32 + ty + 8 * i;
        if (w < WWID)
            X[(((long)(b * HH + h)) * WWID + w) * CC + ct * 32 + tx] = tile[tx][ty + 8 * i];
    }
}

// ---------------- weight prep + bias/mask tables ----------------
__global__ void k_wprep(const float* __restrict__ f1w, const float* __restrict__ f2w,
                        const float* __restrict__ qkvw, const float* __restrict__ projw,
                        const float* __restrict__ rpb,
                        unsigned short* __restrict__ wbf, float* __restrict__ biasg) {
    int id = blockIdx.x * 256 + threadIdx.x;   // 425984 total
    if (id < 73728) {
        int layer = id / 36864, rem = id % 36864;
        int ks = rem / 12288, r2 = rem % 12288;
        int nt = r2 / 512, r3 = r2 % 512;
        int lane = r3 / 8, e = r3 % 8;
        int o = nt * 16 + (lane & 15);
        int c = ks * 32 + 8 * (lane >> 4) + e;
        wbf[(long)layer * 36864 + rem] = pk_bf16(f1w[((long)layer * 384 + o) * 96 + c]);
    } else if (id < 147456) {
        int id2 = id - 73728;
        int layer = id2 / 36864, rem = id2 % 36864;
        int ks = rem / 3072, r2 = rem % 3072;
        int nt = r2 / 512, r3 = r2 % 512;
        int lane = r3 / 8, e = r3 % 8;
        int o = nt * 16 + (lane & 15);
        int c = ks * 32 + 8 * (lane >> 4) + e;
        wbf[73728 + (long)layer * 36864 + rem] = pk_bf16(f2w[((long)layer * 96 + o) * 384 + c]);
    } else if (id < 202752) {
        wbf[id] = pk_bf16(qkvw[id - 147456]);
    } else if (id < 221184) {
        wbf[id] = pk_bf16(projw[id - 202752]);
    } else {
        int id2 = id - 221184;                 // 0..204799
        int layer = id2 / 102400, r = id2 % 102400;
        int type = r / 25600; r %= 25600;
        int h = r / 6400; r %= 6400;
        int i = r / 80, j = r % 80;
        float v;
        if (i >= 72 || j >= 72) {
            v = -10000.f;
        } else {
            int thi = i / 12, twi = i % 12, thj = j / 12, twj = j % 12;
            int ridx = (thi - thj + 5) * 23 + (twi - twj + 11);
            v = rpb[(layer * 253 + ridx) * 4 + h];
            if (layer == 1) {
                int eh = type & 1, ew = type >> 1;
                int ri = (eh ? (thi < 3 ? 1 : 2) * 3 : 0) + (ew ? (twi < 6 ? 1 : 2) : 0);
                int rj = (eh ? (thj < 3 ? 1 : 2) * 3 : 0) + (ew ? (twj < 6 ? 1 : 2) : 0);
                if (ri != rj) v -= 100.f;
            }
        }
        biasg[id2] = v;
    }
}

// ---------------- fused LN1 + MFMA window attention (R10, validated) ----------------
template <int SHIFT>
__global__ __launch_bounds__(1024, 8) void k_attn(float* __restrict__ X,
        const float* __restrict__ gg, const float* __restrict__ bb,
        const unsigned short* __restrict__ wqkv, const float* __restrict__ qkvb,
        const unsigned short* __restrict__ wprj, const float* __restrict__ projb,
        const float* __restrict__ biasT) {
    __shared__ __align__(16) unsigned char smem[73984];
    unsigned short* As  = (unsigned short*)smem;
    unsigned short* os  = (unsigned short*)smem;
    unsigned short* qs  = (unsigned short*)(smem + 16640);
    unsigned short* ks  = (unsigned short*)(smem + 32000);
    unsigned short* vt  = (unsigned short*)(smem + 47360);

    int bid = blockIdx.x;
    int b = bid / NWIN, wi = bid % NWIN;
    int nwh = wi / NWW_, nww = wi % NWW_;
    int tid = threadIdx.x;
    int wv = tid >> 6, lane = tid & 63;
    int li = lane & 15, gq = lane >> 4;

    int type = SHIFT ? ((nwh == 30 ? 1 : 0) | (nww == 29 ? 2 : 0)) : 0;
    const float* bias_t = biasT + type * 25600;

    {
        unsigned* vz = (unsigned*)vt;
        for (int idx = tid; idx < 6656; idx += 1024) vz[idx] = 0u;
        unsigned* az = (unsigned*)(As + 72 * 104);
        for (int idx = tid; idx < 416; idx += 1024) az[idx] = 0u;
    }

    // ---- phase 0: gather window + LN1 -> As ----
    {
        int sub = lane >> 3, p = lane & 7;
        int t = wv * 8 + sub;
        if (t < 72) {
            int th = t / 12, tw = t % 12;
            int hr = nwh * WH_ + th, wr = nww * WW_ + tw;
            int ho = SHIFT ? (hr + SH_) % HH : hr;
            int wo = SHIFT ? (wr + SW_) % WWID : wr;
            const float* xr = X + (((long)b * HH + ho) * WWID + wo) * CC;
            float4 a  = *(const float4*)(xr + p * 4);
            float4 c4 = *(const float4*)(xr + p * 4 + 32);
            float4 e4 = *(const float4*)(xr + p * 4 + 64);
            float s  = a.x + a.y + a.z + a.w + c4.x + c4.y + c4.z + c4.w + e4.x + e4.y + e4.z + e4.w;
            float sq = a.x*a.x + a.y*a.y + a.z*a.z + a.w*a.w + c4.x*c4.x + c4.y*c4.y + c4.z*c4.z + c4.w*c4.w
                     + e4.x*e4.x + e4.y*e4.y + e4.z*e4.z + e4.w*e4.w;
            #pragma unroll
            for (int off = 1; off < 8; off <<= 1) {
                s  += __shfl_xor(s, off);
                sq += __shfl_xor(sq, off);
            }
            float mean = s * (1.f / CC);
            float var = sq * (1.f / CC) - mean * mean;
            float rs = rsqrtf(var + 1e-5f);
            float4 g0 = *(const float4*)(gg + p * 4);
            float4 g1v = *(const float4*)(gg + p * 4 + 32);
            float4 g2v = *(const float4*)(gg + p * 4 + 64);
            float4 t0 = *(const float4*)(bb + p * 4);
            float4 t1 = *(const float4*)(bb + p * 4 + 32);
            float4 t2 = *(const float4*)(bb + p * 4 + 64);
            *(uint2*)(As + t * 104 + p * 4) =
                pk4((a.x - mean) * rs * g0.x + t0.x, (a.y - mean) * rs * g0.y + t0.y,
                    (a.z - mean) * rs * g0.z + t0.z, (a.w - mean) * rs * g0.w + t0.w);
            *(uint2*)(As + t * 104 + p * 4 + 32) =
                pk4((c4.x - mean) * rs * g1v.x + t1.x, (c4.y - mean) * rs * g1v.y + t1.y,
                    (c4.z - mean) * rs * g1v.z + t1.z, (c4.w - mean) * rs * g1v.w + t1.w);
            *(uint2*)(As + t * 104 + p * 4 + 64) =
                pk4((e4.x - mean) * rs * g2v.x + t2.x, (e4.y - mean) * rs * g2v.y + t2.y,
                    (e4.z - mean) * rs * g2v.z + t2.z, (e4.w - mean) * rs * g2v.w + t2.w);
        }
    }
    __syncthreads();

    // ---- phase 1: QKV ----
    for (int mt = wv; mt < 18; mt += 16) {
        short8v aw[3];
        #pragma unroll
        for (int ksi = 0; ksi < 3; ++ksi)
            aw[ksi] = *(const short8v*)(wqkv + (mt * 16 + li) * 96 + ksi * 32 + 8 * gq);
        float bias4[4];
        #pragma unroll
        for (int r = 0; r < 4; ++r) bias4[r] = qkvb[mt * 16 + 4 * gq + r];
        f32x4 acc[5];
        #pragma unroll
        for (int nt = 0; nt < 5; ++nt) acc[nt] = (f32x4){0.f, 0.f, 0.f, 0.f};
        #pragma unroll
        for (int nt = 0; nt < 5; ++nt)
            #pragma unroll
            for (int ksi = 0; ksi < 3; ++ksi) {
                short8v by = *(const short8v*)(As + (nt * 16 + li) * 104 + ksi * 32 + 8 * gq);
                acc[nt] = __builtin_amdgcn_mfma_f32_16x16x32_bf16(aw[ksi], by, acc[nt], 0, 0, 0);
            }
        int which = mt / 6, mtl = mt % 6;
        int oo0 = mtl * 16 + 4 * gq;
        int h = oo0 / 24, d0 = oo0 % 24;
        #pragma unroll
        for (int nt = 0; nt < 5; ++nt) {
            int token = nt * 16 + li;
            if (which == 2) {
                #pragma unroll
                for (int r = 0; r < 4; ++r)
                    vt[(h * 32 + d0 + r) * 104 + token] = pk_bf16(acc[nt][r] + bias4[r]);
            } else {
                float v0 = acc[nt][0] + bias4[0], v1 = acc[nt][1] + bias4[1];
                float v2 = acc[nt][2] + bias4[2], v3 = acc[nt][3] + bias4[3];
                if (which == 0) { v0 *= SCALE_; v1 *= SCALE_; v2 *= SCALE_; v3 *= SCALE_; }
                unsigned short* dst = (which == 0 ? qs : ks) + (h * 80 + token) * 24 + d0;
                *(uint2*)dst = pk4(v0, v1, v2, v3);
            }
        }
    }
    __syncthreads();

    // ---- phase 2: fused S + PV, shuffle-transposed P ----
    for (int u = wv; u < 20; u += 16) {
        int h = u / 5, nt = u % 5;
        short8v bq = {0,0,0,0,0,0,0,0};
        if (gq < 3) bq = *(const short8v*)(qs + (h * 80 + nt * 16 + li) * 24 + 8 * gq);
        const float* brow = bias_t + (h * 80 + nt * 16 + li) * 80;
        float p[20];
        float sum = 0.f;
        #pragma unroll
        for (int mt = 0; mt < 5; ++mt) {
            short8v ak = {0,0,0,0,0,0,0,0};
            if (gq < 3) ak = *(const short8v*)(ks + (h * 80 + mt * 16 + li) * 24 + 8 * gq);
            f32x4 ct = __builtin_amdgcn_mfma_f32_16x16x32_bf16(ak, bq, (f32x4){0.f,0.f,0.f,0.f}, 0, 0, 0);
            float4 bv = *(const float4*)(brow + mt * 16 + 4 * gq);
            p[mt*4+0] = __expf(ct[0] + bv.x);
            p[mt*4+1] = __expf(ct[1] + bv.y);
            p[mt*4+2] = __expf(ct[2] + bv.z);
            p[mt*4+3] = __expf(ct[3] + bv.w);
            sum += p[mt*4+0] + p[mt*4+1] + p[mt*4+2] + p[mt*4+3];
        }
        sum += __shfl_xor(sum, 16);
        sum += __shfl_xor(sum, 32);
        float inv = sum > 0.f ? 1.f / sum : 0.f;
        #pragma unroll
        for (int k2 = 0; k2 < 20; ++k2) p[k2] *= inv;

        short8v ap[3];
        #pragma unroll
        for (int ksi = 0; ksi < 3; ++ksi) {
            float pv[8];
            #pragma unroll
            for (int e = 0; e < 8; ++e) {
                int srcl = li + 16 * (2 * (gq & 1) + (e >> 2));
                float s0 = __shfl(p[8 * ksi + (e & 3)], srcl);
                float s1 = (ksi < 2) ? __shfl(p[8 * ksi + 4 + (e & 3)], srcl) : 0.f;
                pv[e] = (gq >= 2) ? s1 : s0;
            }
            uint2 lo = pk4(pv[0], pv[1], pv[2], pv[3]);
            uint2 hi = pk4(pv[4], pv[5], pv[6], pv[7]);
            union { uint4 u; short8v s; } cvt;
            cvt.u = make_uint4(lo.x, lo.y, hi.x, hi.y);
            ap[ksi] = cvt.s;
        }
        #pragma unroll
        for (int nt2 = 0; nt2 < 2; ++nt2) {
            f32x4 acc = (f32x4){0.f, 0.f, 0.f, 0.f};
            #pragma unroll
            for (int ksi = 0; ksi < 3; ++ksi) {
                short8v bv2 = *(const short8v*)(vt + (h * 32 + nt2 * 16 + li) * 104 + ksi * 32 + 8 * gq);
                acc = __builtin_amdgcn_mfma_f32_16x16x32_bf16(ap[ksi], bv2, acc, 0, 0, 0);
            }
            int d = nt2 * 16 + li;
            if (d < 24) {
                #pragma unroll
                for (int r = 0; r < 4; ++r)
                    os[(nt * 16 + 4 * gq + r) * 104 + h * 24 + d] = pk_bf16(acc[r]);
            }
        }
    }
    __syncthreads();

    // ---- phase 3: proj + residual scatter ----
    for (int u = wv; u < 30; u += 16) {
        int mt = u / 6, nt = u % 6;
        f32x4 acc = (f32x4){0.f, 0.f, 0.f, 0.f};
        #pragma unroll
        for (int ksi = 0; ksi < 3; ++ksi) {
            short8v ao = *(const short8v*)(os + (mt * 16 + li) * 104 + ksi * 32 + 8 * gq);
            short8v bw = *(const short8v*)(wprj + (nt * 16 + li) * 96 + ksi * 32 + 8 * gq);
            acc = __builtin_amdgcn_mfma_f32_16x16x32_bf16(ao, bw, acc, 0, 0, 0);
        }
        int o = nt * 16 + li;
        float bo = projb[o];
        #pragma unroll
        for (int r = 0; r < 4; ++r) {
            int token = mt * 16 + 4 * gq + r;
            if (token < 72) {
                int th = token / 12, tw = token % 12;
                int hr = nwh * WH_ + th, wr = nww * WW_ + tw;
                int ho = SHIFT ? (hr + SH_) % HH : hr;
                int wo = SHIFT ? (wr + SW_) % WWID : wr;
                X[(((long)b * HH + ho) * WWID + wo) * CC + o] += acc[r] + bo;
            }
        }
    }
}

// ---------------- fused LN2 + MFMA MLP v3: 48 tokens, 49KB LDS -> 3 blocks/CU ----------------
template <int LAST>
__global__ __launch_bounds__(512, 6) void k_mlp2(float* __restrict__ X, float* __restrict__ out, int ntok,
        const float* __restrict__ g, const float* __restrict__ bta,
        const unsigned short* __restrict__ w1f, const float* __restrict__ b1v,
        const unsigned short* __restrict__ w2f, const float* __restrict__ b2v) {
    __shared__ __align__(16) unsigned short As[MTOK * 120];   // 11520 B
    __shared__ __align__(16) unsigned short Hs[MTOK * 392];   // 37632 B
    long tok0 = (long)blockIdx.x * MTOK;
    int tid = threadIdx.x;
    int wv = tid >> 6, lane = tid & 63;
    int li = lane & 15, gq = lane >> 4;

    // ---- LN: 8 lanes per token, 48 tokens (threads 0..383) ----
    if (tid < MTOK * 8) {
        int t = tid >> 3, p = tid & 7;
        long gt = tok0 + t; if (gt >= ntok) gt = ntok - 1;
        const float* xr = X + gt * CC;
        float4 a = *(const float4*)(xr + p * 4);
        float4 b = *(const float4*)(xr + p * 4 + 32);
        float4 c4 = *(const float4*)(xr + p * 4 + 64);
        float s  = a.x + a.y + a.z + a.w + b.x + b.y + b.z + b.w + c4.x + c4.y + c4.z + c4.w;
        float sq = a.x*a.x + a.y*a.y + a.z*a.z + a.w*a.w + b.x*b.x + b.y*b.y + b.z*b.z + b.w*b.w
                 + c4.x*c4.x + c4.y*c4.y + c4.z*c4.z + c4.w*c4.w;
        #pragma unroll
        for (int off = 1; off < 8; off <<= 1) {
            s  += __shfl_xor(s, off);
            sq += __shfl_xor(sq, off);
        }
        float mean = s * (1.f / CC);
        float var = sq * (1.f / CC) - mean * mean;
        float rs = rsqrtf(var + 1e-5f);
        float4 g0 = *(const float4*)(g + p * 4);
        float4 g1 = *(const float4*)(g + p * 4 + 32);
        float4 g2 = *(const float4*)(g + p * 4 + 64);
        float4 t0 = *(const float4*)(bta + p * 4);
        float4 t1 = *(const float4*)(bta + p * 4 + 32);
        float4 t2 = *(const float4*)(bta + p * 4 + 64);
        unsigned short* arow = As + t * 120;
        *(uint2*)(arow + p * 4) =
            pk4((a.x - mean) * rs * g0.x + t0.x, (a.y - mean) * rs * g0.y + t0.y,
                (a.z - mean) * rs * g0.z + t0.z, (a.w - mean) * rs * g0.w + t0.w);
        *(uint2*)(arow + p * 4 + 32) =
            pk4((b.x - mean) * rs * g1.x + t1.x, (b.y - mean) * rs * g1.y + t1.y,
                (b.z - mean) * rs * g1.z + t1.z, (b.w - mean) * rs * g1.w + t1.w);
        *(uint2*)(arow + p * 4 + 64) =
            pk4((c4.x - mean) * rs * g2.x + t2.x, (c4.y - mean) * rs * g2.y + t2.y,
                (c4.z - mean) * rs * g2.z + t2.z, (c4.w - mean) * rs * g2.w + t2.w);
    }
    __syncthreads();

    // ---- fc1: wave wv owns nt = 3*wv .. 3*wv+2, strips s<3 ----
    {
        const short8v* wb = (const short8v*)w1f;
        short8v bfr[3][3];
        #pragma unroll
        for (int j = 0; j < 3; ++j)
            #pragma unroll
            for (int ks = 0; ks < 3; ++ks)
                bfr[j][ks] = wb[(ks * 24 + wv * 3 + j) * 64 + lane];
        float bb[3];
        #pragma unroll
        for (int j = 0; j < 3; ++j) bb[j] = b1v[(wv * 3 + j) * 16 + li];
        #pragma unroll
        for (int s = 0; s < 3; ++s) {
            short8v afr[3];
            #pragma unroll
            for (int ks = 0; ks < 3; ++ks)
                afr[ks] = *(const short8v*)(As + (s * 16 + li) * 120 + ks * 32 + 8 * gq);
            #pragma unroll
            for (int j = 0; j < 3; ++j) {
                f32x4 acc = (f32x4){0.f, 0.f, 0.f, 0.f};
                #pragma unroll
                for (int ks = 0; ks < 3; ++ks)
                    acc = __builtin_amdgcn_mfma_f32_16x16x32_bf16(afr[ks], bfr[j][ks], acc, 0, 0, 0);
                int n = (wv * 3 + j) * 16 + li;
                #pragma unroll
                for (int r = 0; r < 4; ++r) {
                    float sv = acc[r] + bb[j];
                    float z = sv + 0.044715f * sv * sv * sv;
                    float gl = sv / (1.f + __expf(-1.5957691216057308f * z));
                    Hs[(s * 16 + 4 * gq + r) * 392 + n] = pk_bf16(gl);
                }
            }
        }
    }
    __syncthreads();

    // ---- fc2: waves 0-5 own nt = wv; strips s<3; + residual / fused crop ----
    if (wv < 6) {
        const short8v* wb2 = (const short8v*)w2f;
        short8v bfr2[12];
        #pragma unroll
        for (int ks = 0; ks < 12; ++ks)
            bfr2[ks] = wb2[(ks * 6 + wv) * 64 + lane];
        int n = wv * 16 + li;
        float bb = b2v[n];
        int b0 = 0, h0 = 0, w0 = 0;
        if (LAST) {
            b0 = (int)(tok0 / (HH * WWID));
            int rem0 = (int)(tok0 % (HH * WWID));
            h0 = rem0 / WWID; w0 = rem0 % WWID;
        }
        #pragma unroll
        for (int s = 0; s < 3; ++s) {
            f32x4 acc = (f32x4){0.f, 0.f, 0.f, 0.f};
            #pragma unroll
            for (int ks = 0; ks < 12; ++ks) {
                short8v a2 = *(const short8v*)(Hs + (s * 16 + li) * 392 + ks * 32 + 8 * gq);
                acc = __builtin_amdgcn_mfma_f32_16x16x32_bf16(a2, bfr2[ks], acc, 0, 0, 0);
            }
            #pragma unroll
            for (int r = 0; r < 4; ++r) {
                int o = s * 16 + 4 * gq + r;
                long gt = tok0 + o;
                if (gt < ntok) {
                    if (LAST) {
                        int w = w0 + o, h = h0, b = b0;
                        if (w >= WWID) { w -= WWID; h += 1; }
                        if (h >= HH) { h -= HH; b += 1; }
                        int lat = h - PT_;
                        if (lat >= 0 && lat < LAT_)
                            out[((long)(b * CC + n)) * (LAT_ * LON_) + lat * LON_ + w] =
                                X[gt * CC + n] + acc[r] + bb;
                    } else {
                        X[gt * CC + n] += acc[r] + bb;
                    }
                }
            }
        }
    }
}

extern "C" void kernel_launch(void* const* d_in, const int* in_sizes, int n_in,
                              void* d_out, int out_size, void* d_ws, size_t ws_size,
                              hipStream_t stream) {
    const float* x     = (const float*)d_in[0];
    const float* g1    = (const float*)d_in[1];
    const float* b1    = (const float*)d_in[2];
    const float* qkvw  = (const float*)d_in[3];
    const float* qkvb  = (const float*)d_in[4];
    const float* projw = (const float*)d_in[5];
    const float* projb = (const float*)d_in[6];
    const float* rpb   = (const float*)d_in[7];
    const float* g2    = (const float*)d_in[8];
    const float* b2    = (const float*)d_in[9];
    const float* f1w   = (const float*)d_in[10];
    const float* f1b   = (const float*)d_in[11];
    const float* f2w   = (const float*)d_in[12];
    const float* f2b   = (const float*)d_in[13];

    float* X = (float*)d_ws;                                  // 51.4 MB
    unsigned short* wbf = (unsigned short*)(X + (long)BB * HH * WWID * CC);
    float* biasg = (float*)(wbf + 221184);                    // 2 x 102400 f32

    const int ntok = BB * HH * WWID;                          // 133920
    const int mlp_blocks = (ntok + MTOK - 1) / MTOK;          // 2790

    k_pad2<<<BB * HH * 12 * 3, 256, 0, stream>>>(x, X);
    k_wprep<<<1664, 256, 0, stream>>>(f1w, f2w, qkvw, projw, rpb, wbf, biasg);

    for (int i = 0; i < 2; ++i) {
        const unsigned short* wqkv_bf = wbf + 147456 + (long)i * 27648;
        const unsigned short* wprj_bf = wbf + 202752 + (long)i * 9216;
        if (i == 0) {
            k_attn<0><<<BB * NWIN, 1024, 0, stream>>>(X, g1, b1,
                wqkv_bf, qkvb, wprj_bf, projb, biasg);
            k_mlp2<0><<<mlp_blocks, 512, 0, stream>>>(X, nullptr, ntok,
                g2, b2, wbf, f1b, wbf + 73728, f2b);
        } else {
            k_attn<1><<<BB * NWIN, 1024, 0, stream>>>(X, g1 + CC, b1 + CC,
                wqkv_bf, qkvb + 3 * CC, wprj_bf, projb + CC, biasg + 102400);
            k_mlp2<1><<<mlp_blocks, 512, 0, stream>>>(X, (float*)d_out, ntok,
                g2 + CC, b2 + CC, wbf + 36864, f1b + 4 * CC, wbf + 73728 + 36864, f2b + CC);
        }
    }
}

// Round 14
// 292.897 us; speedup vs baseline: 1.2759x; 1.0049x over previous
//
#include <hip/hip_runtime.h>
#include <hip/hip_bf16.h>
#include <math.h>

// ---- problem constants ----
#define BB    2
#define CC    96
#define NHD   4
#define HDIM  24
#define LAT_  181
#define LON_  360
#define PT_   2
#define HH    186
#define WWID  360
#define WH_   6
#define WW_   12
#define NTOK  72
#define SH_   3
#define SW_   6
#define NWH_  31
#define NWW_  30
#define NWIN  930
#define SCALE_ 0.20412414523193154f   // 24^-0.5
#define MTOK  48

typedef __attribute__((ext_vector_type(8))) short short8v;
typedef __attribute__((ext_vector_type(4))) float f32x4;

__device__ __forceinline__ unsigned short pk_bf16(float x) {
    __hip_bfloat16 h = __float2bfloat16(x);
    union { __hip_bfloat16 b; unsigned short u; } cv; cv.b = h; return cv.u;
}
__device__ __forceinline__ uint2 pk4(float a, float b, float c, float d) {
    __hip_bfloat162 lo = __float22bfloat162_rn(make_float2(a, b));
    __hip_bfloat162 hi = __float22bfloat162_rn(make_float2(c, d));
    union { __hip_bfloat162 b; unsigned u; } c0, c1; c0.b = lo; c1.b = hi;
    uint2 r; r.x = c0.u; r.y = c1.u; return r;
}

// ---------------- pad + NCHW->NHWC via LDS tile transpose ----------------
__global__ __launch_bounds__(256) void k_pad2(const float* __restrict__ in, float* __restrict__ X) {
    int bid = blockIdx.x;
    int ct = bid % 3; bid /= 3;
    int wt = bid % 12; bid /= 12;
    int h = bid % HH; int b = bid / HH;
    int lat = h - PT_;
    int tx = threadIdx.x & 31, ty = threadIdx.x >> 5;
    __shared__ float tile[32][33];
    if (lat >= 0 && lat < LAT_) {
        int w = wt * 32 + tx;
        #pragma unroll
        for (int i = 0; i < 4; ++i) {
            int c = ct * 32 + ty + 8 * i;
            float v = 0.f;
            if (w < WWID) v = in[((long)(b * CC + c)) * (LAT_ * LON_) + lat * LON_ + w];
            tile[ty + 8 * i][tx] = v;
        }
    } else {
        #pragma unroll
        for (int i = 0; i < 4; ++i) tile[ty + 8 * i][tx] = 0.f;
    }
    __syncthreads();
    #pragma unroll
    for (int i = 0; i < 4; ++i) {
        int w = wt * 32 + ty + 8 * i;
        if (w < WWID)
            X[(((long)(b * HH + h)) * WWID + w) * CC + ct * 32 + tx] = tile[tx][ty + 8 * i];
    }
}

// ---------------- weight prep + bias/mask tables ----------------
__global__ void k_wprep(const float* __restrict__ f1w, const float* __restrict__ f2w,
                        const float* __restrict__ qkvw, const float* __restrict__ projw,
                        const float* __restrict__ rpb,
                        unsigned short* __restrict__ wbf, float* __restrict__ biasg) {
    int id = blockIdx.x * 256 + threadIdx.x;   // 425984 total
    if (id < 73728) {
        int layer = id / 36864, rem = id % 36864;
        int ks = rem / 12288, r2 = rem % 12288;
        int nt = r2 / 512, r3 = r2 % 512;
        int lane = r3 / 8, e = r3 % 8;
        int o = nt * 16 + (lane & 15);
        int c = ks * 32 + 8 * (lane >> 4) + e;
        wbf[(long)layer * 36864 + rem] = pk_bf16(f1w[((long)layer * 384 + o) * 96 + c]);
    } else if (id < 147456) {
        int id2 = id - 73728;
        int layer = id2 / 36864, rem = id2 % 36864;
        int ks = rem / 3072, r2 = rem % 3072;
        int nt = r2 / 512, r3 = r2 % 512;
        int lane = r3 / 8, e = r3 % 8;
        int o = nt * 16 + (lane & 15);
        int c = ks * 32 + 8 * (lane >> 4) + e;
        wbf[73728 + (long)layer * 36864 + rem] = pk_bf16(f2w[((long)layer * 96 + o) * 384 + c]);
    } else if (id < 202752) {
        wbf[id] = pk_bf16(qkvw[id - 147456]);
    } else if (id < 221184) {
        wbf[id] = pk_bf16(projw[id - 202752]);
    } else {
        int id2 = id - 221184;                 // 0..204799
        int layer = id2 / 102400, r = id2 % 102400;
        int type = r / 25600; r %= 25600;
        int h = r / 6400; r %= 6400;
        int i = r / 80, j = r % 80;
        float v;
        if (i >= 72 || j >= 72) {
            v = -10000.f;
        } else {
            int thi = i / 12, twi = i % 12, thj = j / 12, twj = j % 12;
            int ridx = (thi - thj + 5) * 23 + (twi - twj + 11);
            v = rpb[(layer * 253 + ridx) * 4 + h];
            if (layer == 1) {
                int eh = type & 1, ew = type >> 1;
                int ri = (eh ? (thi < 3 ? 1 : 2) * 3 : 0) + (ew ? (twi < 6 ? 1 : 2) : 0);
                int rj = (eh ? (thj < 3 ? 1 : 2) * 3 : 0) + (ew ? (twj < 6 ? 1 : 2) : 0);
                if (ri != rj) v -= 100.f;
            }
        }
        biasg[id2] = v;
    }
}

// ---------------- fused LN1 + MFMA window attention (R10 + setprio) ----------------
template <int SHIFT>
__global__ __launch_bounds__(1024, 8) void k_attn(float* __restrict__ X,
        const float* __restrict__ gg, const float* __restrict__ bb,
        const unsigned short* __restrict__ wqkv, const float* __restrict__ qkvb,
        const unsigned short* __restrict__ wprj, const float* __restrict__ projb,
        const float* __restrict__ biasT) {
    __shared__ __align__(16) unsigned char smem[73984];
    unsigned short* As  = (unsigned short*)smem;
    unsigned short* os  = (unsigned short*)smem;
    unsigned short* qs  = (unsigned short*)(smem + 16640);
    unsigned short* ks  = (unsigned short*)(smem + 32000);
    unsigned short* vt  = (unsigned short*)(smem + 47360);

    int bid = blockIdx.x;
    int b = bid / NWIN, wi = bid % NWIN;
    int nwh = wi / NWW_, nww = wi % NWW_;
    int tid = threadIdx.x;
    int wv = tid >> 6, lane = tid & 63;
    int li = lane & 15, gq = lane >> 4;

    int type = SHIFT ? ((nwh == 30 ? 1 : 0) | (nww == 29 ? 2 : 0)) : 0;
    const float* bias_t = biasT + type * 25600;

    {
        unsigned* vz = (unsigned*)vt;
        for (int idx = tid; idx < 6656; idx += 1024) vz[idx] = 0u;
        unsigned* az = (unsigned*)(As + 72 * 104);
        for (int idx = tid; idx < 416; idx += 1024) az[idx] = 0u;
    }

    // ---- phase 0: gather window + LN1 -> As ----
    {
        int sub = lane >> 3, p = lane & 7;
        int t = wv * 8 + sub;
        if (t < 72) {
            int th = t / 12, tw = t % 12;
            int hr = nwh * WH_ + th, wr = nww * WW_ + tw;
            int ho = SHIFT ? (hr + SH_) % HH : hr;
            int wo = SHIFT ? (wr + SW_) % WWID : wr;
            const float* xr = X + (((long)b * HH + ho) * WWID + wo) * CC;
            float4 a  = *(const float4*)(xr + p * 4);
            float4 c4 = *(const float4*)(xr + p * 4 + 32);
            float4 e4 = *(const float4*)(xr + p * 4 + 64);
            float s  = a.x + a.y + a.z + a.w + c4.x + c4.y + c4.z + c4.w + e4.x + e4.y + e4.z + e4.w;
            float sq = a.x*a.x + a.y*a.y + a.z*a.z + a.w*a.w + c4.x*c4.x + c4.y*c4.y + c4.z*c4.z + c4.w*c4.w
                     + e4.x*e4.x + e4.y*e4.y + e4.z*e4.z + e4.w*e4.w;
            #pragma unroll
            for (int off = 1; off < 8; off <<= 1) {
                s  += __shfl_xor(s, off);
                sq += __shfl_xor(sq, off);
            }
            float mean = s * (1.f / CC);
            float var = sq * (1.f / CC) - mean * mean;
            float rs = rsqrtf(var + 1e-5f);
            float4 g0 = *(const float4*)(gg + p * 4);
            float4 g1v = *(const float4*)(gg + p * 4 + 32);
            float4 g2v = *(const float4*)(gg + p * 4 + 64);
            float4 t0 = *(const float4*)(bb + p * 4);
            float4 t1 = *(const float4*)(bb + p * 4 + 32);
            float4 t2 = *(const float4*)(bb + p * 4 + 64);
            *(uint2*)(As + t * 104 + p * 4) =
                pk4((a.x - mean) * rs * g0.x + t0.x, (a.y - mean) * rs * g0.y + t0.y,
                    (a.z - mean) * rs * g0.z + t0.z, (a.w - mean) * rs * g0.w + t0.w);
            *(uint2*)(As + t * 104 + p * 4 + 32) =
                pk4((c4.x - mean) * rs * g1v.x + t1.x, (c4.y - mean) * rs * g1v.y + t1.y,
                    (c4.z - mean) * rs * g1v.z + t1.z, (c4.w - mean) * rs * g1v.w + t1.w);
            *(uint2*)(As + t * 104 + p * 4 + 64) =
                pk4((e4.x - mean) * rs * g2v.x + t2.x, (e4.y - mean) * rs * g2v.y + t2.y,
                    (e4.z - mean) * rs * g2v.z + t2.z, (e4.w - mean) * rs * g2v.w + t2.w);
        }
    }
    __syncthreads();

    // ---- phase 1: QKV ----
    for (int mt = wv; mt < 18; mt += 16) {
        short8v aw[3];
        #pragma unroll
        for (int ksi = 0; ksi < 3; ++ksi)
            aw[ksi] = *(const short8v*)(wqkv + (mt * 16 + li) * 96 + ksi * 32 + 8 * gq);
        float bias4[4];
        #pragma unroll
        for (int r = 0; r < 4; ++r) bias4[r] = qkvb[mt * 16 + 4 * gq + r];
        f32x4 acc[5];
        #pragma unroll
        for (int nt = 0; nt < 5; ++nt) acc[nt] = (f32x4){0.f, 0.f, 0.f, 0.f};
        __builtin_amdgcn_s_setprio(1);
        #pragma unroll
        for (int nt = 0; nt < 5; ++nt)
            #pragma unroll
            for (int ksi = 0; ksi < 3; ++ksi) {
                short8v by = *(const short8v*)(As + (nt * 16 + li) * 104 + ksi * 32 + 8 * gq);
                acc[nt] = __builtin_amdgcn_mfma_f32_16x16x32_bf16(aw[ksi], by, acc[nt], 0, 0, 0);
            }
        __builtin_amdgcn_s_setprio(0);
        int which = mt / 6, mtl = mt % 6;
        int oo0 = mtl * 16 + 4 * gq;
        int h = oo0 / 24, d0 = oo0 % 24;
        #pragma unroll
        for (int nt = 0; nt < 5; ++nt) {
            int token = nt * 16 + li;
            if (which == 2) {
                #pragma unroll
                for (int r = 0; r < 4; ++r)
                    vt[(h * 32 + d0 + r) * 104 + token] = pk_bf16(acc[nt][r] + bias4[r]);
            } else {
                float v0 = acc[nt][0] + bias4[0], v1 = acc[nt][1] + bias4[1];
                float v2 = acc[nt][2] + bias4[2], v3 = acc[nt][3] + bias4[3];
                if (which == 0) { v0 *= SCALE_; v1 *= SCALE_; v2 *= SCALE_; v3 *= SCALE_; }
                unsigned short* dst = (which == 0 ? qs : ks) + (h * 80 + token) * 24 + d0;
                *(uint2*)dst = pk4(v0, v1, v2, v3);
            }
        }
    }
    __syncthreads();

    // ---- phase 2: fused S + PV, shuffle-transposed P ----
    for (int u = wv; u < 20; u += 16) {
        int h = u / 5, nt = u % 5;
        short8v bq = {0,0,0,0,0,0,0,0};
        if (gq < 3) bq = *(const short8v*)(qs + (h * 80 + nt * 16 + li) * 24 + 8 * gq);
        const float* brow = bias_t + (h * 80 + nt * 16 + li) * 80;
        float p[20];
        float sum = 0.f;
        #pragma unroll
        for (int mt = 0; mt < 5; ++mt) {
            short8v ak = {0,0,0,0,0,0,0,0};
            if (gq < 3) ak = *(const short8v*)(ks + (h * 80 + mt * 16 + li) * 24 + 8 * gq);
            f32x4 ct = __builtin_amdgcn_mfma_f32_16x16x32_bf16(ak, bq, (f32x4){0.f,0.f,0.f,0.f}, 0, 0, 0);
            float4 bv = *(const float4*)(brow + mt * 16 + 4 * gq);
            p[mt*4+0] = __expf(ct[0] + bv.x);
            p[mt*4+1] = __expf(ct[1] + bv.y);
            p[mt*4+2] = __expf(ct[2] + bv.z);
            p[mt*4+3] = __expf(ct[3] + bv.w);
            sum += p[mt*4+0] + p[mt*4+1] + p[mt*4+2] + p[mt*4+3];
        }
        sum += __shfl_xor(sum, 16);
        sum += __shfl_xor(sum, 32);
        float inv = sum > 0.f ? 1.f / sum : 0.f;
        #pragma unroll
        for (int k2 = 0; k2 < 20; ++k2) p[k2] *= inv;

        short8v ap[3];
        #pragma unroll
        for (int ksi = 0; ksi < 3; ++ksi) {
            float pv[8];
            #pragma unroll
            for (int e = 0; e < 8; ++e) {
                int srcl = li + 16 * (2 * (gq & 1) + (e >> 2));
                float s0 = __shfl(p[8 * ksi + (e & 3)], srcl);
                float s1 = (ksi < 2) ? __shfl(p[8 * ksi + 4 + (e & 3)], srcl) : 0.f;
                pv[e] = (gq >= 2) ? s1 : s0;
            }
            uint2 lo = pk4(pv[0], pv[1], pv[2], pv[3]);
            uint2 hi = pk4(pv[4], pv[5], pv[6], pv[7]);
            union { uint4 u; short8v s; } cvt;
            cvt.u = make_uint4(lo.x, lo.y, hi.x, hi.y);
            ap[ksi] = cvt.s;
        }
        __builtin_amdgcn_s_setprio(1);
        #pragma unroll
        for (int nt2 = 0; nt2 < 2; ++nt2) {
            f32x4 acc = (f32x4){0.f, 0.f, 0.f, 0.f};
            #pragma unroll
            for (int ksi = 0; ksi < 3; ++ksi) {
                short8v bv2 = *(const short8v*)(vt + (h * 32 + nt2 * 16 + li) * 104 + ksi * 32 + 8 * gq);
                acc = __builtin_amdgcn_mfma_f32_16x16x32_bf16(ap[ksi], bv2, acc, 0, 0, 0);
            }
            int d = nt2 * 16 + li;
            if (d < 24) {
                #pragma unroll
                for (int r = 0; r < 4; ++r)
                    os[(nt * 16 + 4 * gq + r) * 104 + h * 24 + d] = pk_bf16(acc[r]);
            }
        }
        __builtin_amdgcn_s_setprio(0);
    }
    __syncthreads();

    // ---- phase 3: proj + residual scatter ----
    for (int u = wv; u < 30; u += 16) {
        int mt = u / 6, nt = u % 6;
        f32x4 acc = (f32x4){0.f, 0.f, 0.f, 0.f};
        __builtin_amdgcn_s_setprio(1);
        #pragma unroll
        for (int ksi = 0; ksi < 3; ++ksi) {
            short8v ao = *(const short8v*)(os + (mt * 16 + li) * 104 + ksi * 32 + 8 * gq);
            short8v bw = *(const short8v*)(wprj + (nt * 16 + li) * 96 + ksi * 32 + 8 * gq);
            acc = __builtin_amdgcn_mfma_f32_16x16x32_bf16(ao, bw, acc, 0, 0, 0);
        }
        __builtin_amdgcn_s_setprio(0);
        int o = nt * 16 + li;
        float bo = projb[o];
        #pragma unroll
        for (int r = 0; r < 4; ++r) {
            int token = mt * 16 + 4 * gq + r;
            if (token < 72) {
                int th = token / 12, tw = token % 12;
                int hr = nwh * WH_ + th, wr = nww * WW_ + tw;
                int ho = SHIFT ? (hr + SH_) % HH : hr;
                int wo = SHIFT ? (wr + SW_) % WWID : wr;
                X[(((long)b * HH + ho) * WWID + wo) * CC + o] += acc[r] + bo;
            }
        }
    }
}

// ---------------- fused LN2 + MFMA MLP v3 + setprio ----------------
template <int LAST>
__global__ __launch_bounds__(512, 6) void k_mlp2(float* __restrict__ X, float* __restrict__ out, int ntok,
        const float* __restrict__ g, const float* __restrict__ bta,
        const unsigned short* __restrict__ w1f, const float* __restrict__ b1v,
        const unsigned short* __restrict__ w2f, const float* __restrict__ b2v) {
    __shared__ __align__(16) unsigned short As[MTOK * 120];   // 11520 B
    __shared__ __align__(16) unsigned short Hs[MTOK * 392];   // 37632 B
    long tok0 = (long)blockIdx.x * MTOK;
    int tid = threadIdx.x;
    int wv = tid >> 6, lane = tid & 63;
    int li = lane & 15, gq = lane >> 4;

    // ---- LN: 8 lanes per token, 48 tokens (threads 0..383) ----
    if (tid < MTOK * 8) {
        int t = tid >> 3, p = tid & 7;
        long gt = tok0 + t; if (gt >= ntok) gt = ntok - 1;
        const float* xr = X + gt * CC;
        float4 a = *(const float4*)(xr + p * 4);
        float4 b = *(const float4*)(xr + p * 4 + 32);
        float4 c4 = *(const float4*)(xr + p * 4 + 64);
        float s  = a.x + a.y + a.z + a.w + b.x + b.y + b.z + b.w + c4.x + c4.y + c4.z + c4.w;
        float sq = a.x*a.x + a.y*a.y + a.z*a.z + a.w*a.w + b.x*b.x + b.y*b.y + b.z*b.z + b.w*b.w
                 + c4.x*c4.x + c4.y*c4.y + c4.z*c4.z + c4.w*c4.w;
        #pragma unroll
        for (int off = 1; off < 8; off <<= 1) {
            s  += __shfl_xor(s, off);
            sq += __shfl_xor(sq, off);
        }
        float mean = s * (1.f / CC);
        float var = sq * (1.f / CC) - mean * mean;
        float rs = rsqrtf(var + 1e-5f);
        float4 g0 = *(const float4*)(g + p * 4);
        float4 g1 = *(const float4*)(g + p * 4 + 32);
        float4 g2 = *(const float4*)(g + p * 4 + 64);
        float4 t0 = *(const float4*)(bta + p * 4);
        float4 t1 = *(const float4*)(bta + p * 4 + 32);
        float4 t2 = *(const float4*)(bta + p * 4 + 64);
        unsigned short* arow = As + t * 120;
        *(uint2*)(arow + p * 4) =
            pk4((a.x - mean) * rs * g0.x + t0.x, (a.y - mean) * rs * g0.y + t0.y,
                (a.z - mean) * rs * g0.z + t0.z, (a.w - mean) * rs * g0.w + t0.w);
        *(uint2*)(arow + p * 4 + 32) =
            pk4((b.x - mean) * rs * g1.x + t1.x, (b.y - mean) * rs * g1.y + t1.y,
                (b.z - mean) * rs * g1.z + t1.z, (b.w - mean) * rs * g1.w + t1.w);
        *(uint2*)(arow + p * 4 + 64) =
            pk4((c4.x - mean) * rs * g2.x + t2.x, (c4.y - mean) * rs * g2.y + t2.y,
                (c4.z - mean) * rs * g2.z + t2.z, (c4.w - mean) * rs * g2.w + t2.w);
    }
    __syncthreads();

    // ---- fc1: wave wv owns nt = 3*wv .. 3*wv+2, strips s<3 ----
    {
        const short8v* wb = (const short8v*)w1f;
        short8v bfr[3][3];
        #pragma unroll
        for (int j = 0; j < 3; ++j)
            #pragma unroll
            for (int ks = 0; ks < 3; ++ks)
                bfr[j][ks] = wb[(ks * 24 + wv * 3 + j) * 64 + lane];
        float bb[3];
        #pragma unroll
        for (int j = 0; j < 3; ++j) bb[j] = b1v[(wv * 3 + j) * 16 + li];
        #pragma unroll
        for (int s = 0; s < 3; ++s) {
            short8v afr[3];
            #pragma unroll
            for (int ks = 0; ks < 3; ++ks)
                afr[ks] = *(const short8v*)(As + (s * 16 + li) * 120 + ks * 32 + 8 * gq);
            f32x4 accs[3];
            __builtin_amdgcn_s_setprio(1);
            #pragma unroll
            for (int j = 0; j < 3; ++j) {
                f32x4 acc = (f32x4){0.f, 0.f, 0.f, 0.f};
                #pragma unroll
                for (int ks = 0; ks < 3; ++ks)
                    acc = __builtin_amdgcn_mfma_f32_16x16x32_bf16(afr[ks], bfr[j][ks], acc, 0, 0, 0);
                accs[j] = acc;
            }
            __builtin_amdgcn_s_setprio(0);
            #pragma unroll
            for (int j = 0; j < 3; ++j) {
                int n = (wv * 3 + j) * 16 + li;
                #pragma unroll
                for (int r = 0; r < 4; ++r) {
                    float sv = accs[j][r] + bb[j];
                    float z = sv + 0.044715f * sv * sv * sv;
                    float gl = sv / (1.f + __expf(-1.5957691216057308f * z));
                    Hs[(s * 16 + 4 * gq + r) * 392 + n] = pk_bf16(gl);
                }
            }
        }
    }
    __syncthreads();

    // ---- fc2: waves 0-5 own nt = wv; strips s<3; + residual / fused crop ----
    if (wv < 6) {
        const short8v* wb2 = (const short8v*)w2f;
        short8v bfr2[12];
        #pragma unroll
        for (int ks = 0; ks < 12; ++ks)
            bfr2[ks] = wb2[(ks * 6 + wv) * 64 + lane];
        int n = wv * 16 + li;
        float bb = b2v[n];
        int b0 = 0, h0 = 0, w0 = 0;
        if (LAST) {
            b0 = (int)(tok0 / (HH * WWID));
            int rem0 = (int)(tok0 % (HH * WWID));
            h0 = rem0 / WWID; w0 = rem0 % WWID;
        }
        #pragma unroll
        for (int s = 0; s < 3; ++s) {
            f32x4 acc = (f32x4){0.f, 0.f, 0.f, 0.f};
            __builtin_amdgcn_s_setprio(1);
            #pragma unroll
            for (int ks = 0; ks < 12; ++ks) {
                short8v a2 = *(const short8v*)(Hs + (s * 16 + li) * 392 + ks * 32 + 8 * gq);
                acc = __builtin_amdgcn_mfma_f32_16x16x32_bf16(a2, bfr2[ks], acc, 0, 0, 0);
            }
            __builtin_amdgcn_s_setprio(0);
            #pragma unroll
            for (int r = 0; r < 4; ++r) {
                int o = s * 16 + 4 * gq + r;
                long gt = tok0 + o;
                if (gt < ntok) {
                    if (LAST) {
                        int w = w0 + o, h = h0, b = b0;
                        if (w >= WWID) { w -= WWID; h += 1; }
                        if (h >= HH) { h -= HH; b += 1; }
                        int lat = h - PT_;
                        if (lat >= 0 && lat < LAT_)
                            out[((long)(b * CC + n)) * (LAT_ * LON_) + lat * LON_ + w] =
                                X[gt * CC + n] + acc[r] + bb;
                    } else {
                        X[gt * CC + n] += acc[r] + bb;
                    }
                }
            }
        }
    }
}

extern "C" void kernel_launch(void* const* d_in, const int* in_sizes, int n_in,
                              void* d_out, int out_size, void* d_ws, size_t ws_size,
                              hipStream_t stream) {
    const float* x     = (const float*)d_in[0];
    const float* g1    = (const float*)d_in[1];
    const float* b1    = (const float*)d_in[2];
    const float* qkvw  = (const float*)d_in[3];
    const float* qkvb  = (const float*)d_in[4];
    const float* projw = (const float*)d_in[5];
    const float* projb = (const float*)d_in[6];
    const float* rpb   = (const float*)d_in[7];
    const float* g2    = (const float*)d_in[8];
    const float* b2    = (const float*)d_in[9];
    const float* f1w   = (const float*)d_in[10];
    const float* f1b   = (const float*)d_in[11];
    const float* f2w   = (const float*)d_in[12];
    const float* f2b   = (const float*)d_in[13];

    float* X = (float*)d_ws;                                  // 51.4 MB
    unsigned short* wbf = (unsigned short*)(X + (long)BB * HH * WWID * CC);
    float* biasg = (float*)(wbf + 221184);                    // 2 x 102400 f32

    const int ntok = BB * HH * WWID;                          // 133920
    const int mlp_blocks = (ntok + MTOK - 1) / MTOK;          // 2790

    k_pad2<<<BB * HH * 12 * 3, 256, 0, stream>>>(x, X);
    k_wprep<<<1664, 256, 0, stream>>>(f1w, f2w, qkvw, projw, rpb, wbf, biasg);

    for (int i = 0; i < 2; ++i) {
        const unsigned short* wqkv_bf = wbf + 147456 + (long)i * 27648;
        const unsigned short* wprj_bf = wbf + 202752 + (long)i * 9216;
        if (i == 0) {
            k_attn<0><<<BB * NWIN, 1024, 0, stream>>>(X, g1, b1,
                wqkv_bf, qkvb, wprj_bf, projb, biasg);
            k_mlp2<0><<<mlp_blocks, 512, 0, stream>>>(X, nullptr, ntok,
                g2, b2, wbf, f1b, wbf + 73728, f2b);
        } else {
            k_attn<1><<<BB * NWIN, 1024, 0, stream>>>(X, g1 + CC, b1 + CC,
                wqkv_bf, qkvb + 3 * CC, wprj_bf, projb + CC, biasg + 102400);
            k_mlp2<1><<<mlp_blocks, 512, 0, stream>>>(X, (float*)d_out, ntok,
                g2 + CC, b2 + CC, wbf + 36864, f1b + 4 * CC, wbf + 73728 + 36864, f2b + CC);
        }
    }
}